// Round 7
// baseline (942.345 us; speedup 1.0000x reference)
//
#include <hip/hip_runtime.h>
#include <hip/hip_bf16.h>
#include <math.h>

#define T_DIM 4096
#define HSZ   7168
#define QLR_K 1536
#define NH    64
#define HD    128
#define QN    (NH*HD)   // 8192
#define TOPK_N 2048
#define MASK_VAL (-3.0e38f)
// 0.125 (w_proj scale) * 128^-0.5 (q scale, folded out of fp8 q for precision)
#define WSCALE 0.011048543456039806f

using short8 = __attribute__((ext_vector_type(8))) short;   // 8 bf16 (4 VGPR)
using f32x4  = __attribute__((ext_vector_type(4))) float;

#define MFMA16(a,b,c) __builtin_amdgcn_mfma_f32_16x16x32_bf16(a,b,c,0,0,0)
#define MFMA8(a,b,c)  __builtin_amdgcn_mfma_f32_16x16x32_fp8_fp8(a,b,c,0,0,0)

__device__ __forceinline__ float rope_invf(int d) {
    return (float)(1.0 / pow(10000.0, (double)d / 32.0));
}
__device__ __forceinline__ unsigned short f2bf(float f) {
    unsigned u = __float_as_uint(f);
    return (unsigned short)((u + 0x7FFFu + ((u >> 16) & 1u)) >> 16);
}
// f32 -> OCP e4m3fn, round-nearest, saturating (never emits NaN). Manual
// (no builtin dependence). ~12 VALU ops, used only in conversion epilogues.
__device__ __forceinline__ unsigned char f2fp8(float x) {
    unsigned u = __float_as_uint(x);
    unsigned sign = (u >> 24) & 0x80u;
    float a = fabsf(x);
    if (a < 0.001953125f) {                 // < 2^-9 -> 0 (skip tiny subnormals)
        if (a < 0.0009765625f) return (unsigned char)sign;
        return (unsigned char)(sign | 1);   // ~2^-9 -> smallest subnormal
    }
    if (a > 448.f) a = 448.f;
    int e; float m = frexpf(a, &e);         // a = m*2^e, m in [0.5,1)
    int mant = (int)rintf(m * 16.f) - 8;    // [0,8]
    int E = e - 1 + 7;
    if (mant == 8) { mant = 0; E += 1; }
    if (E <= 0) {                           // subnormal: val = q * 2^-9
        int q = (int)rintf(a * 512.f); if (q > 7) q = 7;
        return (unsigned char)(sign | q);
    }
    if (E > 15) { E = 15; mant = 6; }       // clamp to 448 (0x7E), never NaN
    return (unsigned char)(sign | (E << 3) | mant);
}

// ============================================================================
// rope_tab
// ============================================================================
__global__ __launch_bounds__(256)
void rope_tab_kernel(const int* __restrict__ positions, float2* __restrict__ tab) {
    int idx = blockIdx.x * 256 + threadIdx.x;
    int t = idx >> 5, dd = idx & 31;
    float p = (float)positions[t];
    float ang = p * rope_invf(dd);
    float s, c; sincosf(ang, &s, &c);
    tab[idx] = make_float2(c, s);
}

// ============================================================================
// conv_afrag: row-major f32 [R][C] -> A-frag bf16 [ig=r>>4][ks=c>>5][lane][8]
// ============================================================================
__global__ __launch_bounds__(256)
void conv_afrag(const float* __restrict__ src, unsigned short* __restrict__ dst,
                int C, int KS, int ctiles) {
    __shared__ float lds[32][258];
    const int tid = threadIdx.x;
    const int rt = blockIdx.x / ctiles, ct = blockIdx.x - rt * ctiles;
    const int r0 = rt * 32, c0 = ct * 256;
#pragma unroll
    for (int it = 0; it < 8; ++it) {
        int fid = it * 256 + tid;
        int r = fid >> 6, c4 = (fid & 63) << 2;
        float4 v = *(const float4*)(src + (size_t)(r0 + r) * C + c0 + c4);
        lds[r][c4] = v.x; lds[r][c4 + 1] = v.y; lds[r][c4 + 2] = v.z; lds[r][c4 + 3] = v.w;
    }
    __syncthreads();
    const int lane = tid & 63, wid = tid >> 6;
#pragma unroll
    for (int j = 0; j < 4; ++j) {
        int s = wid * 4 + j;
        int ig_l = s >> 3, ks_l = s & 7;
        int r = ig_l * 16 + (lane & 15);
        int c = ks_l * 32 + ((lane >> 4) << 3);
        unsigned short o[8];
#pragma unroll
        for (int e = 0; e < 8; ++e) o[e] = f2bf(lds[r][c + e]);
        size_t ig = rt * 2 + ig_l, ks = (size_t)ct * 8 + ks_l;
        *(short8*)(dst + ((ig * KS + ks) * 64 + lane) * 8) = *(short8*)o;
    }
}

// ============================================================================
// conv_bfrag_wq: wq_b f32 [1536][8192] -> B-frag [ng][ks][lane][8]
// ============================================================================
__global__ __launch_bounds__(256)
void conv_bfrag_wq(const float* __restrict__ wq, unsigned short* __restrict__ dst) {
    __shared__ float lds[32][258];
    const int tid = threadIdx.x;
    const int kt = blockIdx.x >> 5, nt = blockIdx.x & 31;
    const int k0 = kt * 32, n0 = nt * 256;
#pragma unroll
    for (int it = 0; it < 8; ++it) {
        int fid = it * 256 + tid;
        int k = fid >> 6, c4 = (fid & 63) << 2;
        float4 v = *(const float4*)(wq + (size_t)(k0 + k) * QN + n0 + c4);
        lds[k][c4] = v.x; lds[k][c4 + 1] = v.y; lds[k][c4 + 2] = v.z; lds[k][c4 + 3] = v.w;
    }
    __syncthreads();
    const int lane = tid & 63, wid = tid >> 6;
#pragma unroll
    for (int j = 0; j < 4; ++j) {
        int s = wid * 4 + j;
        int n_l = s * 16 + (lane & 15);
        int kb = (lane >> 4) << 3;
        unsigned short o[8];
#pragma unroll
        for (int e = 0; e < 8; ++e) o[e] = f2bf(lds[kb + e][n_l]);
        size_t ng = (size_t)nt * 16 + s;
        *(short8*)(dst + ((ng * 48 + kt) * 64 + lane) * 8) = *(short8*)o;
    }
}

// ============================================================================
// conv_wkw: wk ++ w_proj -> B-frag [ng 12][ks 224][lane][8]
// ============================================================================
__global__ __launch_bounds__(256)
void conv_wkw(const float* __restrict__ wk, const float* __restrict__ wp,
              unsigned short* __restrict__ dst) {
    int gid = blockIdx.x * 4 + (threadIdx.x >> 6);
    int lane = threadIdx.x & 63;
    int ng = gid / 224, ks = gid - ng * 224;
    int col = ng * 16 + (lane & 15);
    int k = ks * 32 + ((lane >> 4) << 3);
    unsigned short o[8];
#pragma unroll
    for (int e = 0; e < 8; ++e) {
        float v = (col < 128) ? wk[(size_t)(k + e) * 128 + col]
                              : wp[(size_t)(k + e) * 64 + (col - 128)];
        o[e] = f2bf(v);
    }
    *(short8*)(dst + ((size_t)gid * 64 + lane) * 8) = *(short8*)o;
}

// ============================================================================
// kw_gemm_mfma: split-K=4 partials of hs @ [wk|wp]
// ============================================================================
__global__ __launch_bounds__(256)
void kw_gemm_mfma(const unsigned short* __restrict__ hsfrag,
                  const unsigned short* __restrict__ wkwfrag,
                  float* __restrict__ part) {
    const int kz = blockIdx.x, mt = blockIdx.y;
    const int lane = threadIdx.x & 63, wid = threadIdx.x >> 6;
    const int ig = mt * 4 + wid;
    const f32x4 zed = {0.f, 0.f, 0.f, 0.f};
    f32x4 acc[12];
#pragma unroll
    for (int n = 0; n < 12; ++n) acc[n] = zed;
    for (int ks = kz * 56; ks < kz * 56 + 56; ++ks) {
        short8 a = *(const short8*)(hsfrag + (((size_t)ig * 224 + ks) * 64 + lane) * 8);
#pragma unroll
        for (int ng = 0; ng < 12; ++ng) {
            short8 b = *(const short8*)(wkwfrag + (((size_t)ng * 224 + ks) * 64 + lane) * 8);
            acc[ng] = MFMA16(a, b, acc[ng]);
        }
    }
    const int colc = lane & 15, rsub = (lane >> 4) << 2;
    float* pb = part + (size_t)kz * T_DIM * 192;
#pragma unroll
    for (int ng = 0; ng < 12; ++ng)
#pragma unroll
        for (int r = 0; r < 4; ++r) {
            int row = ig * 16 + rsub + r;
            pb[(size_t)row * 192 + ng * 16 + colc] = acc[ng][r];
        }
}

// ============================================================================
// reduce_w: wT[h][row] = WSCALE * sum_z part[z][row][128+h]
// ============================================================================
__global__ __launch_bounds__(256)
void reduce_w(const float* __restrict__ part, float* __restrict__ wT) {
    __shared__ float lds[64][65];
    const int r0 = blockIdx.x * 64;
    const int tid = threadIdx.x;
#pragma unroll
    for (int it = 0; it < 16; ++it) {
        int fid = it * 256 + tid;
        int rl = fid >> 6, h = fid & 63;
        float s = 0.f;
#pragma unroll
        for (int z = 0; z < 4; ++z)
            s += part[((size_t)z * T_DIM + r0 + rl) * 192 + 128 + h];
        lds[rl][h] = s * WSCALE;
    }
    __syncthreads();
#pragma unroll
    for (int it = 0; it < 16; ++it) {
        int fid = it * 256 + tid;
        int h = fid >> 6, rl = fid & 63;
        wT[(size_t)h * T_DIM + r0 + rl] = lds[rl][h];
    }
}

// ============================================================================
// ln_rope_k: reduce + LN + rope; write fp8 B-frag kfrag [jg][ks][lane][8B]
// ============================================================================
__global__ __launch_bounds__(256)
void ln_rope_k(const float* __restrict__ part, const float2* __restrict__ tab,
               const float* __restrict__ gamma, const float* __restrict__ beta,
               unsigned char* __restrict__ kfrag) {
    __shared__ float ln[4][128];
    const int tid = threadIdx.x;
    const int wr = tid >> 6, lane = tid & 63;
    const int row = blockIdx.x * 4 + wr;
    float2 v = make_float2(0.f, 0.f);
#pragma unroll
    for (int z = 0; z < 4; ++z) {
        float2 p = *(const float2*)(part + ((size_t)z * T_DIM + row) * 192 + lane * 2);
        v.x += p.x; v.y += p.y;
    }
    float s = v.x + v.y;
#pragma unroll
    for (int off = 1; off < 64; off <<= 1) s += __shfl_xor(s, off);
    float mu = s * (1.0f / 128.0f);
    float d0 = v.x - mu, d1 = v.y - mu;
    float s2 = d0 * d0 + d1 * d1;
#pragma unroll
    for (int off = 1; off < 64; off <<= 1) s2 += __shfl_xor(s2, off);
    float rstd = 1.0f / sqrtf(s2 * (1.0f / 128.0f) + 1e-6f);
    ln[wr][lane * 2]     = d0 * rstd * gamma[lane * 2]     + beta[lane * 2];
    ln[wr][lane * 2 + 1] = d1 * rstd * gamma[lane * 2 + 1] + beta[lane * 2 + 1];
    __syncthreads();
    int d = lane * 2;
    float o0, o1;
    float v0 = ln[wr][d], v1 = ln[wr][d + 1];
    if (d < 64) {
        int dd = d & 31;
        float2 c0 = tab[(size_t)row * 32 + dd];
        float2 c1 = tab[(size_t)row * 32 + dd + 1];
        if (d < 32) {
            o0 = v0 * c0.x - ln[wr][d + 32] * c0.y;
            o1 = v1 * c1.x - ln[wr][d + 33] * c1.y;
        } else {
            o0 = v0 * c0.x + ln[wr][d - 32] * c0.y;
            o1 = v1 * c1.x + ln[wr][d - 31] * c1.y;
        }
    } else { o0 = v0; o1 = v1; }
    int jg = row >> 4, ks = d >> 5, sub = d & 31;
    int lp = ((sub >> 3) << 4) + (row & 15);
    size_t bidx = (((size_t)jg * 4 + ks) * 64 + lp) * 8 + (sub & 7);
    unsigned short pk = (unsigned short)f2fp8(o0) | ((unsigned short)f2fp8(o1) << 8);
    *(unsigned short*)(kfrag + bidx) = pk;
}

// ============================================================================
// q_gemm_mfma: qfrag = rope(qr @ wq_b) in fp8 A-frag layout (scale folded
// into wT). Flat grid 2048 with XCD-chunked swizzle: each XCD serves 8 heads,
// so its 8 wq panels (3.1MB) stay L2-resident.
// ============================================================================
__global__ __launch_bounds__(256)
void q_gemm_mfma(const unsigned short* __restrict__ qrfrag,
                 const unsigned short* __restrict__ wqfrag,
                 const float2* __restrict__ tab,
                 unsigned char* __restrict__ qfrag) {
    const int hw = blockIdx.x;
    const int orig = (hw & 7) * 256 + (hw >> 3);   // bijective, 2048%8==0
    const int head = orig >> 5, mt = orig & 31;
    const int tid = threadIdx.x, lane = tid & 63, wid = tid >> 6;
    const int wm = wid >> 1, wn = wid & 1;
    const f32x4 zed = {0.f, 0.f, 0.f, 0.f};
    f32x4 acc[4][4];
#pragma unroll
    for (int m = 0; m < 4; m++)
#pragma unroll
        for (int n = 0; n < 4; n++) acc[m][n] = zed;

    const int ig0 = mt * 8 + wm * 4;
    const int ng0 = head * 8 + wn * 4;
    for (int ks = 0; ks < 48; ++ks) {
        short8 a[4], b[4];
#pragma unroll
        for (int m = 0; m < 4; m++)
            a[m] = *(const short8*)(qrfrag + (((size_t)(ig0 + m) * 48 + ks) * 64 + lane) * 8);
#pragma unroll
        for (int n = 0; n < 4; n++)
            b[n] = *(const short8*)(wqfrag + (((size_t)(ng0 + n) * 48 + ks) * 64 + lane) * 8);
#pragma unroll
        for (int m = 0; m < 4; m++)
#pragma unroll
            for (int n = 0; n < 4; n++)
                acc[m][n] = MFMA16(a[m], b[n], acc[m][n]);
    }
    const int colc = lane & 15;
    const int rsub = (lane >> 4) << 2;
#pragma unroll
    for (int m = 0; m < 4; m++) {
#pragma unroll
        for (int r = 0; r < 4; r++) {
            int row = mt * 128 + wm * 64 + m * 16 + rsub + r;
            int rl = rsub + r;
            size_t base = ((size_t)(row >> 4) * 64 + head) * 4;
            if (wn == 0) {
#pragma unroll
                for (int n2 = 0; n2 < 2; n2++) {
                    int dd = n2 * 16 + colc;
                    float2 cs = tab[(size_t)row * 32 + dd];
                    float x1 = acc[m][n2][r], x2 = acc[m][n2 + 2][r];
                    float olo = x1 * cs.x - x2 * cs.y;
                    float ohi = x2 * cs.x + x1 * cs.y;
                    int lp = ((dd >> 3) << 4) + rl;
                    qfrag[((base + 0) * 64 + lp) * 8 + (dd & 7)] = f2fp8(olo);
                    qfrag[((base + 1) * 64 + lp) * 8 + (dd & 7)] = f2fp8(ohi);
                }
            } else {
#pragma unroll
                for (int n = 0; n < 4; n++) {
                    int d = 64 + n * 16 + colc;
                    int ks2 = d >> 5, sub = d & 31;
                    int lp = ((sub >> 3) << 4) + rl;
                    qfrag[((base + ks2) * 64 + lp) * 8 + (sub & 7)] = f2fp8(acc[m][n][r]);
                }
            }
        }
    }
}

// ============================================================================
// scores_fill: MASK_VAL for fully-masked 128x128 tiles (bx > by).
// ============================================================================
__global__ __launch_bounds__(256)
void scores_fill(float* __restrict__ S) {
    const int bx = blockIdx.x, by = blockIdx.y;
    if (bx <= by) return;
    const int tid = threadIdx.x;
    float4 mv = make_float4(MASK_VAL, MASK_VAL, MASK_VAL, MASK_VAL);
#pragma unroll
    for (int l = 0; l < 16; l++) {
        int idx = l * 256 + tid;
        int r = idx >> 5, cg = idx & 31;
        *(float4*)(S + (size_t)(by * 128 + r) * T_DIM + bx * 128 + cg * 4) = mv;
    }
}

// ============================================================================
// scores_mfma v4: fp8 QK. 128x256 tile, 8 waves. Key fixes vs v3:
//  - wT staged to LDS once per block -> the m-loop has NO vmem consumer, so
//    the Q prefetch is never drained mid-loop (the round-6 stall).
//  - fp8 halves stage to 16KB/h; LDS = 32K dbuf + 32K w = 64KB (2 blocks/CU).
//  - XCD-chunked swizzle: each XCD serves 4 by-rows -> per-h Q slices L2-hit.
// ============================================================================
__global__ __launch_bounds__(512, 4)
void scores_mfma(const unsigned char* __restrict__ qfrag,
                 const unsigned char* __restrict__ kfrag,
                 const float* __restrict__ wT, float* __restrict__ S) {
    const int hw = blockIdx.x;
    const int orig = (hw & 7) * 64 + (hw >> 3);    // bijective, 512%8==0
    const int by = orig >> 4, jt = orig & 15;
    if (jt > (by >> 1)) return;
    __shared__ long qs[2][32][64];                  // 2 x 16KB fp8 Q slices
    __shared__ float wlds[64][128];                 // w slice for this i-panel
    const int tid = threadIdx.x;
    const int lane = tid & 63, wid = tid >> 6;
    const int wm = wid >> 2, wn = wid & 3;
    const int i0 = by * 128, j0 = jt * 256;
    const int ig0b = by * 8;
    const f32x4 zed = {0.f, 0.f, 0.f, 0.f};

    // stage w slice [64 h][128 rows] (coalesced 512B rows)
#pragma unroll
    for (int it = 0; it < 16; ++it) {
        int fid = it * 512 + tid;
        int hh = fid >> 7, rl = fid & 127;
        wlds[hh][rl] = wT[(size_t)hh * T_DIM + i0 + rl];
    }
    // K fragments (fp8, register-resident)
    long kf[4][4];
#pragma unroll
    for (int n = 0; n < 4; ++n) {
        int jg = (j0 >> 4) + wn * 4 + n;
#pragma unroll
        for (int ks = 0; ks < 4; ++ks)
            kf[n][ks] = *(const long*)(kfrag + (((size_t)jg * 4 + ks) * 64 + lane) * 8);
    }
    f32x4 acc[4][4];
#pragma unroll
    for (int m = 0; m < 4; m++)
#pragma unroll
        for (int n = 0; n < 4; n++) acc[m][n] = zed;

    const int rsub = (lane >> 4) << 2;
    long r[4];
    // prologue: stage h=0 (wave w stages ig_local=w, ks=0..3)
#pragma unroll
    for (int j = 0; j < 4; ++j)
        r[j] = *(const long*)(qfrag + ((((size_t)(ig0b + wid) * 64 + 0) * 4 + j) * 64 + lane) * 8);
#pragma unroll
    for (int j = 0; j < 4; ++j) qs[0][wid * 4 + j][lane] = r[j];
    __syncthreads();

    for (int h = 0; h < NH; ++h) {
        const int b = h & 1;
        if (h < NH - 1) {
#pragma unroll
            for (int j = 0; j < 4; ++j)
                r[j] = *(const long*)(qfrag + ((((size_t)(ig0b + wid) * 64 + (h + 1)) * 4 + j) * 64 + lane) * 8);
        }
#pragma unroll
        for (int m = 0; m < 4; ++m) {
            const int c0 = (wm * 4 + m) * 4;
            long a[4];
#pragma unroll
            for (int ks = 0; ks < 4; ++ks) a[ks] = qs[b][c0 + ks][lane];
            f32x4 wv = *(const f32x4*)&wlds[h][wm * 64 + m * 16 + rsub];
#pragma unroll
            for (int nh = 0; nh < 2; ++nh) {
                f32x4 s0 = zed, s1 = zed;
#pragma unroll
                for (int ks = 0; ks < 4; ++ks) {
                    s0 = MFMA8(a[ks], kf[nh * 2][ks], s0);
                    s1 = MFMA8(a[ks], kf[nh * 2 + 1][ks], s1);
                }
#pragma unroll
                for (int rr = 0; rr < 4; ++rr) {
                    acc[m][nh * 2][rr]     += wv[rr] * fmaxf(s0[rr], 0.0f);
                    acc[m][nh * 2 + 1][rr] += wv[rr] * fmaxf(s1[rr], 0.0f);
                }
            }
        }
        if (h < NH - 1) {
#pragma unroll
            for (int j = 0; j < 4; ++j) qs[b ^ 1][wid * 4 + j][lane] = r[j];
        }
        __syncthreads();
    }
    const int colc = lane & 15;
#pragma unroll
    for (int m = 0; m < 4; m++) {
#pragma unroll
        for (int n = 0; n < 4; n++) {
            int col = j0 + wn * 64 + n * 16 + colc;
#pragma unroll
            for (int rr = 0; rr < 4; rr++) {
                int row = i0 + wm * 64 + m * 16 + rsub + rr;
                float v = acc[m][n][rr];
                if (col > row) v = MASK_VAL;
                S[(size_t)row * T_DIM + col] = v;
            }
        }
    }
}

// ============================================================================
// topk: u32 keys (20 value bits + 12 idx bits); causal shortcut + final merge
// ============================================================================
__global__ __launch_bounds__(1024)
void topk_kernel(const float* __restrict__ S, float* __restrict__ outIdx) {
    __shared__ unsigned keys[4096];
    const int row = blockIdx.x;
    const int tid = threadIdx.x;
    const unsigned N = (row < TOPK_N) ? 2048u : 4096u;
    for (unsigned p = tid; p < N; p += 1024) {
        float v = S[(size_t)row * T_DIM + p];
        unsigned u = __float_as_uint(v);
        u = (u & 0x80000000u) ? ~u : (u | 0x80000000u);
        keys[p] = ((~u) & 0xFFFFF000u) | p;
    }
    __syncthreads();
    for (unsigned k = 2; k <= 2048u; k <<= 1) {
        for (unsigned j = k >> 1; j > 0; j >>= 1) {
            for (unsigned t = tid; t < N / 2; t += 1024) {
                unsigned i = 2 * t - (t & (j - 1));
                unsigned a = keys[i], b = keys[i + j];
                bool up = ((i & k) == 0);
                unsigned lo = a < b ? a : b, hi = a < b ? b : a;
                keys[i]     = up ? lo : hi;
                keys[i + j] = up ? hi : lo;
            }
            __syncthreads();
        }
    }
    if (N == 4096u) {
        for (unsigned t = tid; t < 2048u; t += 1024) {
            unsigned a = keys[t], b = keys[t + 2048];
            keys[t] = a < b ? a : b;
        }
        __syncthreads();
        for (unsigned j = 1024; j > 0; j >>= 1) {
            for (unsigned t = tid; t < 1024u; t += 1024) {
                unsigned i = 2 * t - (t & (j - 1));
                unsigned a = keys[i], b = keys[i + j];
                keys[i]     = a < b ? a : b;
                keys[i + j] = a < b ? b : a;
            }
            __syncthreads();
        }
    }
    for (int p = tid; p < TOPK_N; p += 1024) {
        outIdx[(size_t)row * TOPK_N + p] = (float)(keys[p] & 0xFFFu);
    }
}

// ============================================================================
extern "C" void kernel_launch(void* const* d_in, const int* in_sizes, int n_in,
                              void* d_out, int out_size, void* d_ws, size_t ws_size,
                              hipStream_t stream) {
    const float* hs      = (const float*)d_in[0];
    const float* qr      = (const float*)d_in[1];
    const int*   pos     = (const int*)  d_in[2];
    const float* wq_b    = (const float*)d_in[3];
    const float* wk      = (const float*)d_in[4];
    const float* k_gamma = (const float*)d_in[5];
    const float* k_beta  = (const float*)d_in[6];
    const float* w_proj  = (const float*)d_in[7];

    float* out     = (float*)d_out;
    float* out_idx = out;
    float* S       = out + (size_t)T_DIM * TOPK_N;

    char* wsp = (char*)d_ws;
    unsigned char*  qfrag  = (unsigned char*)wsp;  wsp += (size_t)67108864;  // 33.5MB fp8 (region shared w/ hsfrag 59MB)
    unsigned short* hsfrag = (unsigned short*)qfrag;  // alias: hs consumed before qfrag written
    unsigned short* qrfrag = (unsigned short*)wsp; wsp += (size_t)12582912;
    unsigned short* wqfrag = (unsigned short*)wsp; wsp += (size_t)25165824;
    unsigned short* wkwfrag= (unsigned short*)wsp; wsp += (size_t)2752512;
    float*          part   = (float*)wsp;          wsp += (size_t)12582912;
    float*          wT     = (float*)wsp;          wsp += (size_t)1048576;
    unsigned char*  kfrag  = (unsigned char*)wsp;  wsp += (size_t)1048576;   // 0.5MB used
    float2*         tab    = (float2*)wsp;         wsp += (size_t)1048576;

    rope_tab_kernel<<<512, 256, 0, stream>>>(pos, tab);
    conv_afrag <<<3584, 256, 0, stream>>>(hs, hsfrag, HSZ, 224, 28);
    conv_wkw   <<<672,  256, 0, stream>>>(wk, w_proj, wkwfrag);
    kw_gemm_mfma<<<dim3(4, 64), 256, 0, stream>>>(hsfrag, wkwfrag, part);
    reduce_w   <<<64,   256, 0, stream>>>(part, wT);
    ln_rope_k  <<<T_DIM / 4, 256, 0, stream>>>(part, tab, k_gamma, k_beta, kfrag);
    conv_afrag <<<768,  256, 0, stream>>>(qr, qrfrag, QLR_K, 48, 6);
    conv_bfrag_wq<<<1536, 256, 0, stream>>>(wq_b, wqfrag);
    q_gemm_mfma<<<2048, 256, 0, stream>>>(qrfrag, wqfrag, tab, qfrag);
    scores_fill<<<dim3(32, 32), 256, 0, stream>>>(S);
    scores_mfma<<<512, 512, 0, stream>>>(qfrag, kfrag, wT, S);
    topk_kernel<<<T_DIM, 1024, 0, stream>>>(S, out_idx);
}

// Round 8
// 802.344 us; speedup vs baseline: 1.1745x; 1.1745x over previous
//
#include <hip/hip_runtime.h>
#include <hip/hip_bf16.h>
#include <math.h>

#define T_DIM 4096
#define HSZ   7168
#define QLR_K 1536
#define NH    64
#define HD    128
#define QN    (NH*HD)   // 8192
#define TOPK_N 2048
#define MASK_VAL (-3.0e38f)
// 0.125 (w_proj scale) * 128^-0.5 (q scale, folded out of fp8 q for precision)
#define WSCALE 0.011048543456039806f

using short8 = __attribute__((ext_vector_type(8))) short;   // 8 bf16 (4 VGPR)
using f32x4  = __attribute__((ext_vector_type(4))) float;

#define MFMA16(a,b,c) __builtin_amdgcn_mfma_f32_16x16x32_bf16(a,b,c,0,0,0)
#define MFMA8(a,b,c)  __builtin_amdgcn_mfma_f32_16x16x32_fp8_fp8(a,b,c,0,0,0)

__device__ __forceinline__ float rope_invf(int d) {
    return (float)(1.0 / pow(10000.0, (double)d / 32.0));
}
__device__ __forceinline__ unsigned short f2bf(float f) {
    unsigned u = __float_as_uint(f);
    return (unsigned short)((u + 0x7FFFu + ((u >> 16) & 1u)) >> 16);
}
// f32 -> OCP e4m3fn, round-nearest, saturating (never emits NaN).
__device__ __forceinline__ unsigned char f2fp8(float x) {
    unsigned u = __float_as_uint(x);
    unsigned sign = (u >> 24) & 0x80u;
    float a = fabsf(x);
    if (a < 0.001953125f) {
        if (a < 0.0009765625f) return (unsigned char)sign;
        return (unsigned char)(sign | 1);
    }
    if (a > 448.f) a = 448.f;
    int e; float m = frexpf(a, &e);
    int mant = (int)rintf(m * 16.f) - 8;
    int E = e - 1 + 7;
    if (mant == 8) { mant = 0; E += 1; }
    if (E <= 0) {
        int q = (int)rintf(a * 512.f); if (q > 7) q = 7;
        return (unsigned char)(sign | q);
    }
    if (E > 15) { E = 15; mant = 6; }
    return (unsigned char)(sign | (E << 3) | mant);
}

// ============================================================================
// rope_tab
// ============================================================================
__global__ __launch_bounds__(256)
void rope_tab_kernel(const int* __restrict__ positions, float2* __restrict__ tab) {
    int idx = blockIdx.x * 256 + threadIdx.x;
    int t = idx >> 5, dd = idx & 31;
    float p = (float)positions[t];
    float ang = p * rope_invf(dd);
    float s, c; sincosf(ang, &s, &c);
    tab[idx] = make_float2(c, s);
}

// ============================================================================
// conv_afrag: row-major f32 [R][C] -> A-frag bf16 [ig=r>>4][ks=c>>5][lane][8]
// ============================================================================
__global__ __launch_bounds__(256)
void conv_afrag(const float* __restrict__ src, unsigned short* __restrict__ dst,
                int C, int KS, int ctiles) {
    __shared__ float lds[32][258];
    const int tid = threadIdx.x;
    const int rt = blockIdx.x / ctiles, ct = blockIdx.x - rt * ctiles;
    const int r0 = rt * 32, c0 = ct * 256;
#pragma unroll
    for (int it = 0; it < 8; ++it) {
        int fid = it * 256 + tid;
        int r = fid >> 6, c4 = (fid & 63) << 2;
        float4 v = *(const float4*)(src + (size_t)(r0 + r) * C + c0 + c4);
        lds[r][c4] = v.x; lds[r][c4 + 1] = v.y; lds[r][c4 + 2] = v.z; lds[r][c4 + 3] = v.w;
    }
    __syncthreads();
    const int lane = tid & 63, wid = tid >> 6;
#pragma unroll
    for (int j = 0; j < 4; ++j) {
        int s = wid * 4 + j;
        int ig_l = s >> 3, ks_l = s & 7;
        int r = ig_l * 16 + (lane & 15);
        int c = ks_l * 32 + ((lane >> 4) << 3);
        unsigned short o[8];
#pragma unroll
        for (int e = 0; e < 8; ++e) o[e] = f2bf(lds[r][c + e]);
        size_t ig = rt * 2 + ig_l, ks = (size_t)ct * 8 + ks_l;
        *(short8*)(dst + ((ig * KS + ks) * 64 + lane) * 8) = *(short8*)o;
    }
}

// ============================================================================
// conv_bfrag_wq: wq_b f32 [1536][8192] -> B-frag [ng][ks][lane][8]
// ============================================================================
__global__ __launch_bounds__(256)
void conv_bfrag_wq(const float* __restrict__ wq, unsigned short* __restrict__ dst) {
    __shared__ float lds[32][258];
    const int tid = threadIdx.x;
    const int kt = blockIdx.x >> 5, nt = blockIdx.x & 31;
    const int k0 = kt * 32, n0 = nt * 256;
#pragma unroll
    for (int it = 0; it < 8; ++it) {
        int fid = it * 256 + tid;
        int k = fid >> 6, c4 = (fid & 63) << 2;
        float4 v = *(const float4*)(wq + (size_t)(k0 + k) * QN + n0 + c4);
        lds[k][c4] = v.x; lds[k][c4 + 1] = v.y; lds[k][c4 + 2] = v.z; lds[k][c4 + 3] = v.w;
    }
    __syncthreads();
    const int lane = tid & 63, wid = tid >> 6;
#pragma unroll
    for (int j = 0; j < 4; ++j) {
        int s = wid * 4 + j;
        int n_l = s * 16 + (lane & 15);
        int kb = (lane >> 4) << 3;
        unsigned short o[8];
#pragma unroll
        for (int e = 0; e < 8; ++e) o[e] = f2bf(lds[kb + e][n_l]);
        size_t ng = (size_t)nt * 16 + s;
        *(short8*)(dst + ((ng * 48 + kt) * 64 + lane) * 8) = *(short8*)o;
    }
}

// ============================================================================
// conv_wkw: wk ++ w_proj -> B-frag [ng 12][ks 224][lane][8]
// ============================================================================
__global__ __launch_bounds__(256)
void conv_wkw(const float* __restrict__ wk, const float* __restrict__ wp,
              unsigned short* __restrict__ dst) {
    int gid = blockIdx.x * 4 + (threadIdx.x >> 6);
    int lane = threadIdx.x & 63;
    int ng = gid / 224, ks = gid - ng * 224;
    int col = ng * 16 + (lane & 15);
    int k = ks * 32 + ((lane >> 4) << 3);
    unsigned short o[8];
#pragma unroll
    for (int e = 0; e < 8; ++e) {
        float v = (col < 128) ? wk[(size_t)(k + e) * 128 + col]
                              : wp[(size_t)(k + e) * 64 + (col - 128)];
        o[e] = f2bf(v);
    }
    *(short8*)(dst + ((size_t)gid * 64 + lane) * 8) = *(short8*)o;
}

// ============================================================================
// kw_gemm_mfma: split-K=4 partials of hs @ [wk|wp]
// ============================================================================
__global__ __launch_bounds__(256)
void kw_gemm_mfma(const unsigned short* __restrict__ hsfrag,
                  const unsigned short* __restrict__ wkwfrag,
                  float* __restrict__ part) {
    const int kz = blockIdx.x, mt = blockIdx.y;
    const int lane = threadIdx.x & 63, wid = threadIdx.x >> 6;
    const int ig = mt * 4 + wid;
    const f32x4 zed = {0.f, 0.f, 0.f, 0.f};
    f32x4 acc[12];
#pragma unroll
    for (int n = 0; n < 12; ++n) acc[n] = zed;
    for (int ks = kz * 56; ks < kz * 56 + 56; ++ks) {
        short8 a = *(const short8*)(hsfrag + (((size_t)ig * 224 + ks) * 64 + lane) * 8);
#pragma unroll
        for (int ng = 0; ng < 12; ++ng) {
            short8 b = *(const short8*)(wkwfrag + (((size_t)ng * 224 + ks) * 64 + lane) * 8);
            acc[ng] = MFMA16(a, b, acc[ng]);
        }
    }
    const int colc = lane & 15, rsub = (lane >> 4) << 2;
    float* pb = part + (size_t)kz * T_DIM * 192;
#pragma unroll
    for (int ng = 0; ng < 12; ++ng)
#pragma unroll
        for (int r = 0; r < 4; ++r) {
            int row = ig * 16 + rsub + r;
            pb[(size_t)row * 192 + ng * 16 + colc] = acc[ng][r];
        }
}

// ============================================================================
// reduce_w: wT[h][row] = WSCALE * sum_z part[z][row][128+h]
// ============================================================================
__global__ __launch_bounds__(256)
void reduce_w(const float* __restrict__ part, float* __restrict__ wT) {
    __shared__ float lds[64][65];
    const int r0 = blockIdx.x * 64;
    const int tid = threadIdx.x;
#pragma unroll
    for (int it = 0; it < 16; ++it) {
        int fid = it * 256 + tid;
        int rl = fid >> 6, h = fid & 63;
        float s = 0.f;
#pragma unroll
        for (int z = 0; z < 4; ++z)
            s += part[((size_t)z * T_DIM + r0 + rl) * 192 + 128 + h];
        lds[rl][h] = s * WSCALE;
    }
    __syncthreads();
#pragma unroll
    for (int it = 0; it < 16; ++it) {
        int fid = it * 256 + tid;
        int h = fid >> 6, rl = fid & 63;
        wT[(size_t)h * T_DIM + r0 + rl] = lds[rl][h];
    }
}

// ============================================================================
// ln_rope_k: reduce + LN + rope; write fp8 B-frag kfrag [jg][ks][lane][8B]
// ============================================================================
__global__ __launch_bounds__(256)
void ln_rope_k(const float* __restrict__ part, const float2* __restrict__ tab,
               const float* __restrict__ gamma, const float* __restrict__ beta,
               unsigned char* __restrict__ kfrag) {
    __shared__ float ln[4][128];
    const int tid = threadIdx.x;
    const int wr = tid >> 6, lane = tid & 63;
    const int row = blockIdx.x * 4 + wr;
    float2 v = make_float2(0.f, 0.f);
#pragma unroll
    for (int z = 0; z < 4; ++z) {
        float2 p = *(const float2*)(part + ((size_t)z * T_DIM + row) * 192 + lane * 2);
        v.x += p.x; v.y += p.y;
    }
    float s = v.x + v.y;
#pragma unroll
    for (int off = 1; off < 64; off <<= 1) s += __shfl_xor(s, off);
    float mu = s * (1.0f / 128.0f);
    float d0 = v.x - mu, d1 = v.y - mu;
    float s2 = d0 * d0 + d1 * d1;
#pragma unroll
    for (int off = 1; off < 64; off <<= 1) s2 += __shfl_xor(s2, off);
    float rstd = 1.0f / sqrtf(s2 * (1.0f / 128.0f) + 1e-6f);
    ln[wr][lane * 2]     = d0 * rstd * gamma[lane * 2]     + beta[lane * 2];
    ln[wr][lane * 2 + 1] = d1 * rstd * gamma[lane * 2 + 1] + beta[lane * 2 + 1];
    __syncthreads();
    int d = lane * 2;
    float o0, o1;
    float v0 = ln[wr][d], v1 = ln[wr][d + 1];
    if (d < 64) {
        int dd = d & 31;
        float2 c0 = tab[(size_t)row * 32 + dd];
        float2 c1 = tab[(size_t)row * 32 + dd + 1];
        if (d < 32) {
            o0 = v0 * c0.x - ln[wr][d + 32] * c0.y;
            o1 = v1 * c1.x - ln[wr][d + 33] * c1.y;
        } else {
            o0 = v0 * c0.x + ln[wr][d - 32] * c0.y;
            o1 = v1 * c1.x + ln[wr][d - 31] * c1.y;
        }
    } else { o0 = v0; o1 = v1; }
    int jg = row >> 4, ks = d >> 5, sub = d & 31;
    int lp = ((sub >> 3) << 4) + (row & 15);
    size_t bidx = (((size_t)jg * 4 + ks) * 64 + lp) * 8 + (sub & 7);
    unsigned short pk = (unsigned short)f2fp8(o0) | ((unsigned short)f2fp8(o1) << 8);
    *(unsigned short*)(kfrag + bidx) = pk;
}

// ============================================================================
// q_gemm_mfma: qfrag = rope(qr @ wq_b) in fp8 A-frag layout.
// ============================================================================
__global__ __launch_bounds__(256)
void q_gemm_mfma(const unsigned short* __restrict__ qrfrag,
                 const unsigned short* __restrict__ wqfrag,
                 const float2* __restrict__ tab,
                 unsigned char* __restrict__ qfrag) {
    const int hw = blockIdx.x;
    const int orig = (hw & 7) * 256 + (hw >> 3);   // bijective, 2048%8==0
    const int head = orig >> 5, mt = orig & 31;
    const int tid = threadIdx.x, lane = tid & 63, wid = tid >> 6;
    const int wm = wid >> 1, wn = wid & 1;
    const f32x4 zed = {0.f, 0.f, 0.f, 0.f};
    f32x4 acc[4][4];
#pragma unroll
    for (int m = 0; m < 4; m++)
#pragma unroll
        for (int n = 0; n < 4; n++) acc[m][n] = zed;

    const int ig0 = mt * 8 + wm * 4;
    const int ng0 = head * 8 + wn * 4;
    for (int ks = 0; ks < 48; ++ks) {
        short8 a[4], b[4];
#pragma unroll
        for (int m = 0; m < 4; m++)
            a[m] = *(const short8*)(qrfrag + (((size_t)(ig0 + m) * 48 + ks) * 64 + lane) * 8);
#pragma unroll
        for (int n = 0; n < 4; n++)
            b[n] = *(const short8*)(wqfrag + (((size_t)(ng0 + n) * 48 + ks) * 64 + lane) * 8);
#pragma unroll
        for (int m = 0; m < 4; m++)
#pragma unroll
            for (int n = 0; n < 4; n++)
                acc[m][n] = MFMA16(a[m], b[n], acc[m][n]);
    }
    const int colc = lane & 15;
    const int rsub = (lane >> 4) << 2;
#pragma unroll
    for (int m = 0; m < 4; m++) {
#pragma unroll
        for (int r = 0; r < 4; r++) {
            int row = mt * 128 + wm * 64 + m * 16 + rsub + r;
            int rl = rsub + r;
            size_t base = ((size_t)(row >> 4) * 64 + head) * 4;
            if (wn == 0) {
#pragma unroll
                for (int n2 = 0; n2 < 2; n2++) {
                    int dd = n2 * 16 + colc;
                    float2 cs = tab[(size_t)row * 32 + dd];
                    float x1 = acc[m][n2][r], x2 = acc[m][n2 + 2][r];
                    float olo = x1 * cs.x - x2 * cs.y;
                    float ohi = x2 * cs.x + x1 * cs.y;
                    int lp = ((dd >> 3) << 4) + rl;
                    qfrag[((base + 0) * 64 + lp) * 8 + (dd & 7)] = f2fp8(olo);
                    qfrag[((base + 1) * 64 + lp) * 8 + (dd & 7)] = f2fp8(ohi);
                }
            } else {
#pragma unroll
                for (int n = 0; n < 4; n++) {
                    int d = 64 + n * 16 + colc;
                    int ks2 = d >> 5, sub = d & 31;
                    int lp = ((sub >> 3) << 4) + rl;
                    qfrag[((base + ks2) * 64 + lp) * 8 + (sub & 7)] = f2fp8(acc[m][n][r]);
                }
            }
        }
    }
}

// ============================================================================
// scores_fill: MASK_VAL for fully-masked 128x128 tiles (bx > by).
// ============================================================================
__global__ __launch_bounds__(256)
void scores_fill(float* __restrict__ S) {
    const int bx = blockIdx.x, by = blockIdx.y;
    if (bx <= by) return;
    const int tid = threadIdx.x;
    float4 mv = make_float4(MASK_VAL, MASK_VAL, MASK_VAL, MASK_VAL);
#pragma unroll
    for (int l = 0; l < 16; l++) {
        int idx = l * 256 + tid;
        int r = idx >> 5, cg = idx & 31;
        *(float4*)(S + (size_t)(by * 128 + r) * T_DIM + bx * 128 + cg * 4) = mv;
    }
}

// ============================================================================
// scores_mfma v5: barrier-free. 128x128 tile, 4 waves (2x2), compact
// triangular grid of 528 uniform blocks (2.06/CU, no swizzle, no early-out).
// Q fp8 fragments read per-wave straight from L2/L3 (no LDS staging, no per-h
// barrier -> round-7's latency serialization gone). w staged once to LDS.
// ============================================================================
__global__ __launch_bounds__(256, 3)
void scores_mfma(const unsigned char* __restrict__ qfrag,
                 const unsigned char* __restrict__ kfrag,
                 const float* __restrict__ wT, float* __restrict__ S) {
    int bid = blockIdx.x;                        // 0..527
    int by = (int)((sqrtf(8.f * bid + 1.f) - 1.f) * 0.5f);
    while ((by + 1) * (by + 2) / 2 <= bid) ++by;
    while (by * (by + 1) / 2 > bid) --by;
    const int jt = bid - by * (by + 1) / 2;      // 0..by
    __shared__ float wlds[64][128];
    const int tid = threadIdx.x;
    const int lane = tid & 63, wid = tid >> 6;   // 4 waves
    const int wm = wid >> 1, wn = wid & 1;       // 2x2 over 128x128
    const int i0 = by * 128, j0 = jt * 128;
    const f32x4 zed = {0.f, 0.f, 0.f, 0.f};
    // stage w slice [64 h][128 rows]
#pragma unroll
    for (int it = 0; it < 32; ++it) {
        int fid = it * 256 + tid;
        int hh = fid >> 7, rl = fid & 127;
        wlds[hh][rl] = wT[(size_t)hh * T_DIM + i0 + rl];
    }
    // K fragments (fp8, register-resident)
    long kf[4][4];
#pragma unroll
    for (int n = 0; n < 4; ++n) {
        int jg = (j0 >> 4) + wn * 4 + n;
#pragma unroll
        for (int ks = 0; ks < 4; ++ks)
            kf[n][ks] = *(const long*)(kfrag + (((size_t)jg * 4 + ks) * 64 + lane) * 8);
    }
    __syncthreads();

    f32x4 acc[4][4];
#pragma unroll
    for (int m = 0; m < 4; m++)
#pragma unroll
        for (int n = 0; n < 4; n++) acc[m][n] = zed;

    const int rsub = (lane >> 4) << 2;
    // per-m Q base pointers (layout [ig][h][ks][lane][8B])
    const unsigned char* qb[4];
#pragma unroll
    for (int m = 0; m < 4; ++m) {
        int ig = by * 8 + wm * 4 + m;
        qb[m] = qfrag + (size_t)ig * 64 * 2048 + lane * 8;
    }
    for (int h = 0; h < NH; ++h) {
#pragma unroll
        for (int m = 0; m < 4; ++m) {
            const unsigned char* qp = qb[m] + (size_t)h * 2048;
            long a[4];
#pragma unroll
            for (int ks = 0; ks < 4; ++ks)
                a[ks] = *(const long*)(qp + ks * 512);
            f32x4 s[4] = {zed, zed, zed, zed};
#pragma unroll
            for (int ks = 0; ks < 4; ++ks)
#pragma unroll
                for (int n = 0; n < 4; ++n)
                    s[n] = MFMA8(a[ks], kf[n][ks], s[n]);
            f32x4 wv = *(const f32x4*)&wlds[h][wm * 64 + m * 16 + rsub];
#pragma unroll
            for (int n = 0; n < 4; ++n)
#pragma unroll
                for (int rr = 0; rr < 4; ++rr)
                    acc[m][n][rr] += wv[rr] * fmaxf(s[n][rr], 0.0f);
        }
    }
    const int colc = lane & 15;
#pragma unroll
    for (int m = 0; m < 4; m++) {
#pragma unroll
        for (int n = 0; n < 4; n++) {
            int col = j0 + wn * 64 + n * 16 + colc;
#pragma unroll
            for (int rr = 0; rr < 4; rr++) {
                int row = i0 + wm * 64 + m * 16 + rsub + rr;
                float v = acc[m][n][rr];
                if (col > row) v = MASK_VAL;
                S[(size_t)row * T_DIM + col] = v;
            }
        }
    }
}

// ============================================================================
// topk v3: u32 keys; thread owns 4 consecutive keys -> k=2,4 and all j<=2
// layers run in registers (uint4 LDS traffic), j>=4 via LDS.
// ============================================================================
__device__ __forceinline__ void ce(unsigned &x, unsigned &y, bool up) {
    unsigned lo = x < y ? x : y, hi = x < y ? y : x;
    x = up ? lo : hi; y = up ? hi : lo;
}

__global__ __launch_bounds__(1024)
void topk_kernel(const float* __restrict__ S, float* __restrict__ outIdx) {
    __shared__ unsigned keys[4096];
    const int row = blockIdx.x;
    const int tid = threadIdx.x;
    const unsigned N = (row < TOPK_N) ? 2048u : 4096u;
    const unsigned e0 = 4u * tid;
    if (e0 < N) {
        float4 f = *(const float4*)(S + (size_t)row * T_DIM + e0);
        unsigned q[4];
        const float* fp = &f.x;
#pragma unroll
        for (int e = 0; e < 4; ++e) {
            unsigned u = __float_as_uint(fp[e]);
            u = (u & 0x80000000u) ? ~u : (u | 0x80000000u);
            q[e] = ((~u) & 0xFFFFF000u) | (e0 + e);
        }
        ce(q[0], q[1], true); ce(q[2], q[3], false);          // k=2
        bool up4 = (e0 & 4u) == 0;                            // k=4
        ce(q[0], q[2], up4); ce(q[1], q[3], up4);
        ce(q[0], q[1], up4); ce(q[2], q[3], up4);
        *(uint4*)&keys[e0] = make_uint4(q[0], q[1], q[2], q[3]);
    }
    __syncthreads();
    for (unsigned k = 8; k <= 2048u; k <<= 1) {
        for (unsigned j = k >> 1; j >= 4; j >>= 1) {
            for (unsigned t = tid; t < N / 2; t += 1024) {
                unsigned i = 2 * t - (t & (j - 1));
                unsigned a = keys[i], b = keys[i + j];
                bool up = ((i & k) == 0);
                unsigned lo = a < b ? a : b, hi = a < b ? b : a;
                keys[i]     = up ? lo : hi;
                keys[i + j] = up ? hi : lo;
            }
            __syncthreads();
        }
        if (e0 < N) {                                          // j=2,1 in regs
            uint4 v = *(uint4*)&keys[e0];
            unsigned q[4] = {v.x, v.y, v.z, v.w};
            bool up = ((e0 & k) == 0);
            ce(q[0], q[2], up); ce(q[1], q[3], up);
            ce(q[0], q[1], up); ce(q[2], q[3], up);
            *(uint4*)&keys[e0] = make_uint4(q[0], q[1], q[2], q[3]);
        }
        __syncthreads();
    }
    if (N == 4096u) {
        for (unsigned t = tid; t < 2048u; t += 1024) {
            unsigned a = keys[t], b = keys[t + 2048];
            keys[t] = a < b ? a : b;
        }
        __syncthreads();
        for (unsigned j = 1024; j >= 4; j >>= 1) {
            for (unsigned t = tid; t < 1024u; t += 1024) {
                unsigned i = 2 * t - (t & (j - 1));
                unsigned a = keys[i], b = keys[i + j];
                keys[i]     = a < b ? a : b;
                keys[i + j] = a < b ? b : a;
            }
            __syncthreads();
        }
        if (e0 < 2048u) {
            uint4 v = *(uint4*)&keys[e0];
            unsigned q[4] = {v.x, v.y, v.z, v.w};
            ce(q[0], q[2], true); ce(q[1], q[3], true);
            ce(q[0], q[1], true); ce(q[2], q[3], true);
            *(uint4*)&keys[e0] = make_uint4(q[0], q[1], q[2], q[3]);
        }
        __syncthreads();
    }
    for (int p = tid; p < TOPK_N; p += 1024) {
        outIdx[(size_t)row * TOPK_N + p] = (float)(keys[p] & 0xFFFu);
    }
}

// ============================================================================
extern "C" void kernel_launch(void* const* d_in, const int* in_sizes, int n_in,
                              void* d_out, int out_size, void* d_ws, size_t ws_size,
                              hipStream_t stream) {
    const float* hs      = (const float*)d_in[0];
    const float* qr      = (const float*)d_in[1];
    const int*   pos     = (const int*)  d_in[2];
    const float* wq_b    = (const float*)d_in[3];
    const float* wk      = (const float*)d_in[4];
    const float* k_gamma = (const float*)d_in[5];
    const float* k_beta  = (const float*)d_in[6];
    const float* w_proj  = (const float*)d_in[7];

    float* out     = (float*)d_out;
    float* out_idx = out;
    float* S       = out + (size_t)T_DIM * TOPK_N;

    char* wsp = (char*)d_ws;
    unsigned char*  qfrag  = (unsigned char*)wsp;  wsp += (size_t)67108864;
    unsigned short* hsfrag = (unsigned short*)qfrag;  // alias: hs consumed before qfrag written
    unsigned short* qrfrag = (unsigned short*)wsp; wsp += (size_t)12582912;
    unsigned short* wqfrag = (unsigned short*)wsp; wsp += (size_t)25165824;
    unsigned short* wkwfrag= (unsigned short*)wsp; wsp += (size_t)2752512;
    float*          part   = (float*)wsp;          wsp += (size_t)12582912;
    float*          wT     = (float*)wsp;          wsp += (size_t)1048576;
    unsigned char*  kfrag  = (unsigned char*)wsp;  wsp += (size_t)1048576;
    float2*         tab    = (float2*)wsp;         wsp += (size_t)1048576;

    rope_tab_kernel<<<512, 256, 0, stream>>>(pos, tab);
    conv_afrag <<<3584, 256, 0, stream>>>(hs, hsfrag, HSZ, 224, 28);
    conv_wkw   <<<672,  256, 0, stream>>>(wk, w_proj, wkwfrag);
    kw_gemm_mfma<<<dim3(4, 64), 256, 0, stream>>>(hsfrag, wkwfrag, part);
    reduce_w   <<<64,   256, 0, stream>>>(part, wT);
    ln_rope_k  <<<T_DIM / 4, 256, 0, stream>>>(part, tab, k_gamma, k_beta, kfrag);
    conv_afrag <<<768,  256, 0, stream>>>(qr, qrfrag, QLR_K, 48, 6);
    conv_bfrag_wq<<<1536, 256, 0, stream>>>(wq_b, wqfrag);
    q_gemm_mfma<<<2048, 256, 0, stream>>>(qrfrag, wqfrag, tab, qfrag);
    scores_fill<<<dim3(32, 32), 256, 0, stream>>>(S);
    scores_mfma<<<528, 256, 0, stream>>>(qfrag, kfrag, wT, S);
    topk_kernel<<<T_DIM, 1024, 0, stream>>>(S, out_idx);
}

// Round 9
// 697.086 us; speedup vs baseline: 1.3518x; 1.1510x over previous
//
#include <hip/hip_runtime.h>
#include <hip/hip_bf16.h>
#include <math.h>

#define T_DIM 4096
#define HSZ   7168
#define QLR_K 1536
#define NH    64
#define HD    128
#define QN    (NH*HD)   // 8192
#define TOPK_N 2048
#define MASK_VAL (-3.0e38f)
// 0.125 (w_proj scale) * 128^-0.5 (q scale, folded out of fp8 q for precision)
#define WSCALE 0.011048543456039806f

using short8 = __attribute__((ext_vector_type(8))) short;   // 8 bf16 (4 VGPR)
using f32x4  = __attribute__((ext_vector_type(4))) float;

#define MFMA16(a,b,c) __builtin_amdgcn_mfma_f32_16x16x32_bf16(a,b,c,0,0,0)
#define MFMA8(a,b,c)  __builtin_amdgcn_mfma_f32_16x16x32_fp8_fp8(a,b,c,0,0,0)

__device__ __forceinline__ float rope_invf(int d) {
    return (float)(1.0 / pow(10000.0, (double)d / 32.0));
}
__device__ __forceinline__ unsigned short f2bf(float f) {
    unsigned u = __float_as_uint(f);
    return (unsigned short)((u + 0x7FFFu + ((u >> 16) & 1u)) >> 16);
}
// HW fp8 e4m3 conversion (v_cvt_pk_fp8_f32, gfx940+): 1 instr vs ~20.
__device__ __forceinline__ unsigned char f2fp8(float x) {
    return (unsigned char)(__builtin_amdgcn_cvt_pk_fp8_f32(x, x, 0, false) & 0xFF);
}
__device__ __forceinline__ unsigned pk4fp8(float a, float b, float c, float d) {
    unsigned w = (unsigned)__builtin_amdgcn_cvt_pk_fp8_f32(a, b, 0, false);
    return (unsigned)__builtin_amdgcn_cvt_pk_fp8_f32(c, d, (int)w, true);
}

// ============================================================================
// rope_tab
// ============================================================================
__global__ __launch_bounds__(256)
void rope_tab_kernel(const int* __restrict__ positions, float2* __restrict__ tab) {
    int idx = blockIdx.x * 256 + threadIdx.x;
    int t = idx >> 5, dd = idx & 31;
    float p = (float)positions[t];
    float ang = p * rope_invf(dd);
    float s, c; sincosf(ang, &s, &c);
    tab[idx] = make_float2(c, s);
}

// ============================================================================
// conv_afrag (bf16, for hs -> kw path): [ig][ks][lane][8]
// ============================================================================
__global__ __launch_bounds__(256)
void conv_afrag(const float* __restrict__ src, unsigned short* __restrict__ dst,
                int C, int KS, int ctiles) {
    __shared__ float lds[32][258];
    const int tid = threadIdx.x;
    const int rt = blockIdx.x / ctiles, ct = blockIdx.x - rt * ctiles;
    const int r0 = rt * 32, c0 = ct * 256;
#pragma unroll
    for (int it = 0; it < 8; ++it) {
        int fid = it * 256 + tid;
        int r = fid >> 6, c4 = (fid & 63) << 2;
        float4 v = *(const float4*)(src + (size_t)(r0 + r) * C + c0 + c4);
        lds[r][c4] = v.x; lds[r][c4 + 1] = v.y; lds[r][c4 + 2] = v.z; lds[r][c4 + 3] = v.w;
    }
    __syncthreads();
    const int lane = tid & 63, wid = tid >> 6;
#pragma unroll
    for (int j = 0; j < 4; ++j) {
        int s = wid * 4 + j;
        int ig_l = s >> 3, ks_l = s & 7;
        int r = ig_l * 16 + (lane & 15);
        int c = ks_l * 32 + ((lane >> 4) << 3);
        unsigned short o[8];
#pragma unroll
        for (int e = 0; e < 8; ++e) o[e] = f2bf(lds[r][c + e]);
        size_t ig = rt * 2 + ig_l, ks = (size_t)ct * 8 + ks_l;
        *(short8*)(dst + ((ig * KS + ks) * 64 + lane) * 8) = *(short8*)o;
    }
}

// ============================================================================
// conv_qr_fp8: qr f32 [4096][1536] -> fp8 A-frag [ig 256][ks 48][lane][8B]
// ============================================================================
__global__ __launch_bounds__(256)
void conv_qr_fp8(const float* __restrict__ src, unsigned char* __restrict__ dst) {
    __shared__ float lds[32][258];
    const int tid = threadIdx.x;
    const int rt = blockIdx.x / 6, ct = blockIdx.x - rt * 6;
    const int r0 = rt * 32, c0 = ct * 256;
#pragma unroll
    for (int it = 0; it < 8; ++it) {
        int fid = it * 256 + tid;
        int r = fid >> 6, c4 = (fid & 63) << 2;
        float4 v = *(const float4*)(src + (size_t)(r0 + r) * QLR_K + c0 + c4);
        lds[r][c4] = v.x; lds[r][c4 + 1] = v.y; lds[r][c4 + 2] = v.z; lds[r][c4 + 3] = v.w;
    }
    __syncthreads();
    const int lane = tid & 63, wid = tid >> 6;
#pragma unroll
    for (int j = 0; j < 4; ++j) {
        int s = wid * 4 + j;
        int ig_l = s >> 3, ks_l = s & 7;
        int r = ig_l * 16 + (lane & 15);
        int c = ks_l * 32 + ((lane >> 4) << 3);
        uint2 o;
        o.x = pk4fp8(lds[r][c], lds[r][c + 1], lds[r][c + 2], lds[r][c + 3]);
        o.y = pk4fp8(lds[r][c + 4], lds[r][c + 5], lds[r][c + 6], lds[r][c + 7]);
        size_t ig = rt * 2 + ig_l, ks = (size_t)ct * 8 + ks_l;
        *(uint2*)(dst + ((ig * 48 + ks) * 64 + lane) * 8) = o;
    }
}

// ============================================================================
// conv_wq_fp8: wq_b f32 [1536][8192] -> fp8 B-frag [ng 512][ks 48][lane][8B]
// ============================================================================
__global__ __launch_bounds__(256)
void conv_wq_fp8(const float* __restrict__ wq, unsigned char* __restrict__ dst) {
    __shared__ float lds[32][258];
    const int tid = threadIdx.x;
    const int kt = blockIdx.x >> 5, nt = blockIdx.x & 31;
    const int k0 = kt * 32, n0 = nt * 256;
#pragma unroll
    for (int it = 0; it < 8; ++it) {
        int fid = it * 256 + tid;
        int k = fid >> 6, c4 = (fid & 63) << 2;
        float4 v = *(const float4*)(wq + (size_t)(k0 + k) * QN + n0 + c4);
        lds[k][c4] = v.x; lds[k][c4 + 1] = v.y; lds[k][c4 + 2] = v.z; lds[k][c4 + 3] = v.w;
    }
    __syncthreads();
    const int lane = tid & 63, wid = tid >> 6;
#pragma unroll
    for (int j = 0; j < 4; ++j) {
        int s = wid * 4 + j;
        int n_l = s * 16 + (lane & 15);
        int kb = (lane >> 4) << 3;
        uint2 o;
        o.x = pk4fp8(lds[kb][n_l], lds[kb + 1][n_l], lds[kb + 2][n_l], lds[kb + 3][n_l]);
        o.y = pk4fp8(lds[kb + 4][n_l], lds[kb + 5][n_l], lds[kb + 6][n_l], lds[kb + 7][n_l]);
        size_t ng = (size_t)nt * 16 + s;
        *(uint2*)(dst + ((ng * 48 + kt) * 64 + lane) * 8) = o;
    }
}

// ============================================================================
// conv_wkw: wk ++ w_proj -> bf16 B-frag [ng 12][ks 224][lane][8]
// ============================================================================
__global__ __launch_bounds__(256)
void conv_wkw(const float* __restrict__ wk, const float* __restrict__ wp,
              unsigned short* __restrict__ dst) {
    int gid = blockIdx.x * 4 + (threadIdx.x >> 6);
    int lane = threadIdx.x & 63;
    int ng = gid / 224, ks = gid - ng * 224;
    int col = ng * 16 + (lane & 15);
    int k = ks * 32 + ((lane >> 4) << 3);
    unsigned short o[8];
#pragma unroll
    for (int e = 0; e < 8; ++e) {
        float v = (col < 128) ? wk[(size_t)(k + e) * 128 + col]
                              : wp[(size_t)(k + e) * 64 + (col - 128)];
        o[e] = f2bf(v);
    }
    *(short8*)(dst + ((size_t)gid * 64 + lane) * 8) = *(short8*)o;
}

// ============================================================================
// kw_gemm_mfma: split-K=4 partials of hs @ [wk|wp]
// ============================================================================
__global__ __launch_bounds__(256)
void kw_gemm_mfma(const unsigned short* __restrict__ hsfrag,
                  const unsigned short* __restrict__ wkwfrag,
                  float* __restrict__ part) {
    const int kz = blockIdx.x, mt = blockIdx.y;
    const int lane = threadIdx.x & 63, wid = threadIdx.x >> 6;
    const int ig = mt * 4 + wid;
    const f32x4 zed = {0.f, 0.f, 0.f, 0.f};
    f32x4 acc[12];
#pragma unroll
    for (int n = 0; n < 12; ++n) acc[n] = zed;
    for (int ks = kz * 56; ks < kz * 56 + 56; ++ks) {
        short8 a = *(const short8*)(hsfrag + (((size_t)ig * 224 + ks) * 64 + lane) * 8);
#pragma unroll
        for (int ng = 0; ng < 12; ++ng) {
            short8 b = *(const short8*)(wkwfrag + (((size_t)ng * 224 + ks) * 64 + lane) * 8);
            acc[ng] = MFMA16(a, b, acc[ng]);
        }
    }
    const int colc = lane & 15, rsub = (lane >> 4) << 2;
    float* pb = part + (size_t)kz * T_DIM * 192;
#pragma unroll
    for (int ng = 0; ng < 12; ++ng)
#pragma unroll
        for (int r = 0; r < 4; ++r) {
            int row = ig * 16 + rsub + r;
            pb[(size_t)row * 192 + ng * 16 + colc] = acc[ng][r];
        }
}

// ============================================================================
// reduce_w: wT[h][row] = WSCALE * sum_z part[z][row][128+h]
// ============================================================================
__global__ __launch_bounds__(256)
void reduce_w(const float* __restrict__ part, float* __restrict__ wT) {
    __shared__ float lds[64][65];
    const int r0 = blockIdx.x * 64;
    const int tid = threadIdx.x;
#pragma unroll
    for (int it = 0; it < 16; ++it) {
        int fid = it * 256 + tid;
        int rl = fid >> 6, h = fid & 63;
        float s = 0.f;
#pragma unroll
        for (int z = 0; z < 4; ++z)
            s += part[((size_t)z * T_DIM + r0 + rl) * 192 + 128 + h];
        lds[rl][h] = s * WSCALE;
    }
    __syncthreads();
#pragma unroll
    for (int it = 0; it < 16; ++it) {
        int fid = it * 256 + tid;
        int h = fid >> 6, rl = fid & 63;
        wT[(size_t)h * T_DIM + r0 + rl] = lds[rl][h];
    }
}

// ============================================================================
// ln_rope_k: reduce + LN + rope; write fp8 B-frag kfrag (HW cvt)
// ============================================================================
__global__ __launch_bounds__(256)
void ln_rope_k(const float* __restrict__ part, const float2* __restrict__ tab,
               const float* __restrict__ gamma, const float* __restrict__ beta,
               unsigned char* __restrict__ kfrag) {
    __shared__ float ln[4][128];
    const int tid = threadIdx.x;
    const int wr = tid >> 6, lane = tid & 63;
    const int row = blockIdx.x * 4 + wr;
    float2 v = make_float2(0.f, 0.f);
#pragma unroll
    for (int z = 0; z < 4; ++z) {
        float2 p = *(const float2*)(part + ((size_t)z * T_DIM + row) * 192 + lane * 2);
        v.x += p.x; v.y += p.y;
    }
    float s = v.x + v.y;
#pragma unroll
    for (int off = 1; off < 64; off <<= 1) s += __shfl_xor(s, off);
    float mu = s * (1.0f / 128.0f);
    float d0 = v.x - mu, d1 = v.y - mu;
    float s2 = d0 * d0 + d1 * d1;
#pragma unroll
    for (int off = 1; off < 64; off <<= 1) s2 += __shfl_xor(s2, off);
    float rstd = 1.0f / sqrtf(s2 * (1.0f / 128.0f) + 1e-6f);
    ln[wr][lane * 2]     = d0 * rstd * gamma[lane * 2]     + beta[lane * 2];
    ln[wr][lane * 2 + 1] = d1 * rstd * gamma[lane * 2 + 1] + beta[lane * 2 + 1];
    __syncthreads();
    int d = lane * 2;
    float o0, o1;
    float v0 = ln[wr][d], v1 = ln[wr][d + 1];
    if (d < 64) {
        int dd = d & 31;
        float2 c0 = tab[(size_t)row * 32 + dd];
        float2 c1 = tab[(size_t)row * 32 + dd + 1];
        if (d < 32) {
            o0 = v0 * c0.x - ln[wr][d + 32] * c0.y;
            o1 = v1 * c1.x - ln[wr][d + 33] * c1.y;
        } else {
            o0 = v0 * c0.x + ln[wr][d - 32] * c0.y;
            o1 = v1 * c1.x + ln[wr][d - 31] * c1.y;
        }
    } else { o0 = v0; o1 = v1; }
    int jg = row >> 4, ks = d >> 5, sub = d & 31;
    int lp = ((sub >> 3) << 4) + (row & 15);
    size_t bidx = (((size_t)jg * 4 + ks) * 64 + lp) * 8 + (sub & 7);
    unsigned pk = (unsigned)__builtin_amdgcn_cvt_pk_fp8_f32(o0, o1, 0, false);
    *(unsigned short*)(kfrag + bidx) = (unsigned short)(pk & 0xFFFFu);
}

// ============================================================================
// q_gemm_mfma v2: fp8 x fp8 -> qfrag fp8 A-frag. HW cvt epilogue.
// Grid 2048 (XCD-chunked: 8 heads' wq panels L2-resident per XCD).
// ============================================================================
__global__ __launch_bounds__(256, 4)
void q_gemm_mfma(const unsigned char* __restrict__ qr8,
                 const unsigned char* __restrict__ wq8,
                 const float2* __restrict__ tab,
                 unsigned char* __restrict__ qfrag) {
    const int hw = blockIdx.x;
    const int orig = (hw & 7) * 256 + (hw >> 3);   // bijective, 2048%8==0
    const int head = orig >> 5, mt = orig & 31;
    const int tid = threadIdx.x, lane = tid & 63, wid = tid >> 6;
    const int wm = wid >> 1, wn = wid & 1;
    const f32x4 zed = {0.f, 0.f, 0.f, 0.f};
    f32x4 acc[4][4];
#pragma unroll
    for (int m = 0; m < 4; m++)
#pragma unroll
        for (int n = 0; n < 4; n++) acc[m][n] = zed;

    const int ig0 = mt * 8 + wm * 4;
    const int ng0 = head * 8 + wn * 4;
    const unsigned char* ap = qr8 + ((size_t)ig0 * 48 * 64 + lane) * 8;
    const unsigned char* bp = wq8 + ((size_t)ng0 * 48 * 64 + lane) * 8;
    for (int ks = 0; ks < 48; ++ks) {
        long a[4], b[4];
#pragma unroll
        for (int m = 0; m < 4; m++)
            a[m] = *(const long*)(ap + ((size_t)m * 48 + ks) * 512);
#pragma unroll
        for (int n = 0; n < 4; n++)
            b[n] = *(const long*)(bp + ((size_t)n * 48 + ks) * 512);
#pragma unroll
        for (int m = 0; m < 4; m++)
#pragma unroll
            for (int n = 0; n < 4; n++)
                acc[m][n] = MFMA8(a[m], b[n], acc[m][n]);
    }
    const int colc = lane & 15;
    const int rsub = (lane >> 4) << 2;
#pragma unroll
    for (int m = 0; m < 4; m++) {
#pragma unroll
        for (int r = 0; r < 4; r++) {
            int row = mt * 128 + wm * 64 + m * 16 + rsub + r;
            int rl = rsub + r;
            size_t base = ((size_t)(row >> 4) * 64 + head) * 4;
            if (wn == 0) {
#pragma unroll
                for (int n2 = 0; n2 < 2; n2++) {
                    int dd = n2 * 16 + colc;
                    float2 cs = tab[(size_t)row * 32 + dd];
                    float x1 = acc[m][n2][r], x2 = acc[m][n2 + 2][r];
                    float olo = x1 * cs.x - x2 * cs.y;
                    float ohi = x2 * cs.x + x1 * cs.y;
                    int lp = ((dd >> 3) << 4) + rl;
                    qfrag[((base + 0) * 64 + lp) * 8 + (dd & 7)] = f2fp8(olo);
                    qfrag[((base + 1) * 64 + lp) * 8 + (dd & 7)] = f2fp8(ohi);
                }
            } else {
#pragma unroll
                for (int n = 0; n < 4; n++) {
                    int d = 64 + n * 16 + colc;
                    int ks2 = d >> 5, sub = d & 31;
                    int lp = ((sub >> 3) << 4) + rl;
                    qfrag[((base + ks2) * 64 + lp) * 8 + (sub & 7)] = f2fp8(acc[m][n][r]);
                }
            }
        }
    }
}

// ============================================================================
// scores_fill
// ============================================================================
__global__ __launch_bounds__(256)
void scores_fill(float* __restrict__ S) {
    const int bx = blockIdx.x, by = blockIdx.y;
    if (bx <= by) return;
    const int tid = threadIdx.x;
    float4 mv = make_float4(MASK_VAL, MASK_VAL, MASK_VAL, MASK_VAL);
#pragma unroll
    for (int l = 0; l < 16; l++) {
        int idx = l * 256 + tid;
        int r = idx >> 5, cg = idx & 31;
        *(float4*)(S + (size_t)(by * 128 + r) * T_DIM + bx * 128 + cg * 4) = mv;
    }
}

// ============================================================================
// scores_mfma v5: barrier-free, compact triangular grid (528 blocks).
// ============================================================================
__global__ __launch_bounds__(256, 3)
void scores_mfma(const unsigned char* __restrict__ qfrag,
                 const unsigned char* __restrict__ kfrag,
                 const float* __restrict__ wT, float* __restrict__ S) {
    int bid = blockIdx.x;                        // 0..527
    int by = (int)((sqrtf(8.f * bid + 1.f) - 1.f) * 0.5f);
    while ((by + 1) * (by + 2) / 2 <= bid) ++by;
    while (by * (by + 1) / 2 > bid) --by;
    const int jt = bid - by * (by + 1) / 2;      // 0..by
    __shared__ float wlds[64][128];
    const int tid = threadIdx.x;
    const int lane = tid & 63, wid = tid >> 6;
    const int wm = wid >> 1, wn = wid & 1;
    const int i0 = by * 128, j0 = jt * 128;
    const f32x4 zed = {0.f, 0.f, 0.f, 0.f};
#pragma unroll
    for (int it = 0; it < 32; ++it) {
        int fid = it * 256 + tid;
        int hh = fid >> 7, rl = fid & 127;
        wlds[hh][rl] = wT[(size_t)hh * T_DIM + i0 + rl];
    }
    long kf[4][4];
#pragma unroll
    for (int n = 0; n < 4; ++n) {
        int jg = (j0 >> 4) + wn * 4 + n;
#pragma unroll
        for (int ks = 0; ks < 4; ++ks)
            kf[n][ks] = *(const long*)(kfrag + (((size_t)jg * 4 + ks) * 64 + lane) * 8);
    }
    __syncthreads();

    f32x4 acc[4][4];
#pragma unroll
    for (int m = 0; m < 4; m++)
#pragma unroll
        for (int n = 0; n < 4; n++) acc[m][n] = zed;

    const int rsub = (lane >> 4) << 2;
    const unsigned char* qb[4];
#pragma unroll
    for (int m = 0; m < 4; ++m) {
        int ig = by * 8 + wm * 4 + m;
        qb[m] = qfrag + (size_t)ig * 64 * 2048 + lane * 8;
    }
    for (int h = 0; h < NH; ++h) {
#pragma unroll
        for (int m = 0; m < 4; ++m) {
            const unsigned char* qp = qb[m] + (size_t)h * 2048;
            long a[4];
#pragma unroll
            for (int ks = 0; ks < 4; ++ks)
                a[ks] = *(const long*)(qp + ks * 512);
            f32x4 s[4] = {zed, zed, zed, zed};
#pragma unroll
            for (int ks = 0; ks < 4; ++ks)
#pragma unroll
                for (int n = 0; n < 4; ++n)
                    s[n] = MFMA8(a[ks], kf[n][ks], s[n]);
            f32x4 wv = *(const f32x4*)&wlds[h][wm * 64 + m * 16 + rsub];
#pragma unroll
            for (int n = 0; n < 4; ++n)
#pragma unroll
                for (int rr = 0; rr < 4; ++rr)
                    acc[m][n][rr] += wv[rr] * fmaxf(s[n][rr], 0.0f);
        }
    }
    const int colc = lane & 15;
#pragma unroll
    for (int m = 0; m < 4; m++) {
#pragma unroll
        for (int n = 0; n < 4; n++) {
            int col = j0 + wn * 64 + n * 16 + colc;
#pragma unroll
            for (int rr = 0; rr < 4; rr++) {
                int row = i0 + wm * 64 + m * 16 + rsub + rr;
                float v = acc[m][n][rr];
                if (col > row) v = MASK_VAL;
                S[(size_t)row * T_DIM + col] = v;
            }
        }
    }
}

// ============================================================================
// topk v3
// ============================================================================
__device__ __forceinline__ void ce(unsigned &x, unsigned &y, bool up) {
    unsigned lo = x < y ? x : y, hi = x < y ? y : x;
    x = up ? lo : hi; y = up ? hi : lo;
}

__global__ __launch_bounds__(1024)
void topk_kernel(const float* __restrict__ S, float* __restrict__ outIdx) {
    __shared__ unsigned keys[4096];
    const int row = blockIdx.x;
    const int tid = threadIdx.x;
    const unsigned N = (row < TOPK_N) ? 2048u : 4096u;
    const unsigned e0 = 4u * tid;
    if (e0 < N) {
        float4 f = *(const float4*)(S + (size_t)row * T_DIM + e0);
        unsigned q[4];
        const float* fp = &f.x;
#pragma unroll
        for (int e = 0; e < 4; ++e) {
            unsigned u = __float_as_uint(fp[e]);
            u = (u & 0x80000000u) ? ~u : (u | 0x80000000u);
            q[e] = ((~u) & 0xFFFFF000u) | (e0 + e);
        }
        ce(q[0], q[1], true); ce(q[2], q[3], false);
        bool up4 = (e0 & 4u) == 0;
        ce(q[0], q[2], up4); ce(q[1], q[3], up4);
        ce(q[0], q[1], up4); ce(q[2], q[3], up4);
        *(uint4*)&keys[e0] = make_uint4(q[0], q[1], q[2], q[3]);
    }
    __syncthreads();
    for (unsigned k = 8; k <= 2048u; k <<= 1) {
        for (unsigned j = k >> 1; j >= 4; j >>= 1) {
            for (unsigned t = tid; t < N / 2; t += 1024) {
                unsigned i = 2 * t - (t & (j - 1));
                unsigned a = keys[i], b = keys[i + j];
                bool up = ((i & k) == 0);
                unsigned lo = a < b ? a : b, hi = a < b ? b : a;
                keys[i]     = up ? lo : hi;
                keys[i + j] = up ? hi : lo;
            }
            __syncthreads();
        }
        if (e0 < N) {
            uint4 v = *(uint4*)&keys[e0];
            unsigned q[4] = {v.x, v.y, v.z, v.w};
            bool up = ((e0 & k) == 0);
            ce(q[0], q[2], up); ce(q[1], q[3], up);
            ce(q[0], q[1], up); ce(q[2], q[3], up);
            *(uint4*)&keys[e0] = make_uint4(q[0], q[1], q[2], q[3]);
        }
        __syncthreads();
    }
    if (N == 4096u) {
        for (unsigned t = tid; t < 2048u; t += 1024) {
            unsigned a = keys[t], b = keys[t + 2048];
            keys[t] = a < b ? a : b;
        }
        __syncthreads();
        for (unsigned j = 1024; j >= 4; j >>= 1) {
            for (unsigned t = tid; t < 1024u; t += 1024) {
                unsigned i = 2 * t - (t & (j - 1));
                unsigned a = keys[i], b = keys[i + j];
                keys[i]     = a < b ? a : b;
                keys[i + j] = a < b ? b : a;
            }
            __syncthreads();
        }
        if (e0 < 2048u) {
            uint4 v = *(uint4*)&keys[e0];
            unsigned q[4] = {v.x, v.y, v.z, v.w};
            ce(q[0], q[2], true); ce(q[1], q[3], true);
            ce(q[0], q[1], true); ce(q[2], q[3], true);
            *(uint4*)&keys[e0] = make_uint4(q[0], q[1], q[2], q[3]);
        }
        __syncthreads();
    }
    for (int p = tid; p < TOPK_N; p += 1024) {
        outIdx[(size_t)row * TOPK_N + p] = (float)(keys[p] & 0xFFFu);
    }
}

// ============================================================================
extern "C" void kernel_launch(void* const* d_in, const int* in_sizes, int n_in,
                              void* d_out, int out_size, void* d_ws, size_t ws_size,
                              hipStream_t stream) {
    const float* hs      = (const float*)d_in[0];
    const float* qr      = (const float*)d_in[1];
    const int*   pos     = (const int*)  d_in[2];
    const float* wq_b    = (const float*)d_in[3];
    const float* wk      = (const float*)d_in[4];
    const float* k_gamma = (const float*)d_in[5];
    const float* k_beta  = (const float*)d_in[6];
    const float* w_proj  = (const float*)d_in[7];

    float* out     = (float*)d_out;
    float* out_idx = out;
    float* S       = out + (size_t)T_DIM * TOPK_N;

    char* wsp = (char*)d_ws;
    unsigned char*  qfrag  = (unsigned char*)wsp;  wsp += (size_t)67108864;
    unsigned short* hsfrag = (unsigned short*)qfrag;  // alias: hs consumed before qfrag written
    unsigned char*  qrfrag = (unsigned char*)wsp;  wsp += (size_t)12582912;  // 6.3MB used
    unsigned char*  wqfrag = (unsigned char*)wsp;  wsp += (size_t)25165824;  // 12.6MB used
    unsigned short* wkwfrag= (unsigned short*)wsp; wsp += (size_t)2752512;
    float*          part   = (float*)wsp;          wsp += (size_t)12582912;
    float*          wT     = (float*)wsp;          wsp += (size_t)1048576;
    unsigned char*  kfrag  = (unsigned char*)wsp;  wsp += (size_t)1048576;
    float2*         tab    = (float2*)wsp;         wsp += (size_t)1048576;

    rope_tab_kernel<<<512, 256, 0, stream>>>(pos, tab);
    conv_afrag <<<3584, 256, 0, stream>>>(hs, hsfrag, HSZ, 224, 28);
    conv_wkw   <<<672,  256, 0, stream>>>(wk, w_proj, wkwfrag);
    kw_gemm_mfma<<<dim3(4, 64), 256, 0, stream>>>(hsfrag, wkwfrag, part);
    reduce_w   <<<64,   256, 0, stream>>>(part, wT);
    ln_rope_k  <<<T_DIM / 4, 256, 0, stream>>>(part, tab, k_gamma, k_beta, kfrag);
    conv_qr_fp8<<<768,  256, 0, stream>>>(qr, qrfrag);
    conv_wq_fp8<<<1536, 256, 0, stream>>>(wq_b, wqfrag);
    q_gemm_mfma<<<2048, 256, 0, stream>>>(qrfrag, wqfrag, tab, qfrag);
    scores_fill<<<dim3(32, 32), 256, 0, stream>>>(S);
    scores_mfma<<<528, 256, 0, stream>>>(qfrag, kfrag, wT, S);
    topk_kernel<<<T_DIM, 1024, 0, stream>>>(S, out_idx);
}

// Round 10
// 650.609 us; speedup vs baseline: 1.4484x; 1.0714x over previous
//
#include <hip/hip_runtime.h>
#include <hip/hip_bf16.h>
#include <math.h>

#define T_DIM 4096
#define HSZ   7168
#define QLR_K 1536
#define NH    64
#define HD    128
#define QN    (NH*HD)   // 8192
#define TOPK_N 2048
#define MASK_VAL (-3.0e38f)
// 0.125 (w_proj scale) * 128^-0.5 (q scale, folded out of fp8 q for precision)
#define WSCALE 0.011048543456039806f

using short8 = __attribute__((ext_vector_type(8))) short;   // 8 bf16 (4 VGPR)
using f32x4  = __attribute__((ext_vector_type(4))) float;

#define MFMA16(a,b,c) __builtin_amdgcn_mfma_f32_16x16x32_bf16(a,b,c,0,0,0)
#define MFMA8(a,b,c)  __builtin_amdgcn_mfma_f32_16x16x32_fp8_fp8(a,b,c,0,0,0)

__device__ __forceinline__ float rope_invf(int d) {
    return (float)(1.0 / pow(10000.0, (double)d / 32.0));
}
__device__ __forceinline__ unsigned short f2bf(float f) {
    unsigned u = __float_as_uint(f);
    return (unsigned short)((u + 0x7FFFu + ((u >> 16) & 1u)) >> 16);
}
// HW fp8 e4m3 conversion (v_cvt_pk_fp8_f32, gfx940+)
__device__ __forceinline__ unsigned char f2fp8(float x) {
    return (unsigned char)(__builtin_amdgcn_cvt_pk_fp8_f32(x, x, 0, false) & 0xFF);
}
__device__ __forceinline__ unsigned pk4fp8(float a, float b, float c, float d) {
    unsigned w = (unsigned)__builtin_amdgcn_cvt_pk_fp8_f32(a, b, 0, false);
    return (unsigned)__builtin_amdgcn_cvt_pk_fp8_f32(c, d, (int)w, true);
}

// ============================================================================
// rope_tab
// ============================================================================
__global__ __launch_bounds__(256)
void rope_tab_kernel(const int* __restrict__ positions, float2* __restrict__ tab) {
    int idx = blockIdx.x * 256 + threadIdx.x;
    int t = idx >> 5, dd = idx & 31;
    float p = (float)positions[t];
    float ang = p * rope_invf(dd);
    float s, c; sincosf(ang, &s, &c);
    tab[idx] = make_float2(c, s);
}

// ============================================================================
// conv_afrag (bf16, for hs -> kw path)
// ============================================================================
__global__ __launch_bounds__(256)
void conv_afrag(const float* __restrict__ src, unsigned short* __restrict__ dst,
                int C, int KS, int ctiles) {
    __shared__ float lds[32][258];
    const int tid = threadIdx.x;
    const int rt = blockIdx.x / ctiles, ct = blockIdx.x - rt * ctiles;
    const int r0 = rt * 32, c0 = ct * 256;
#pragma unroll
    for (int it = 0; it < 8; ++it) {
        int fid = it * 256 + tid;
        int r = fid >> 6, c4 = (fid & 63) << 2;
        float4 v = *(const float4*)(src + (size_t)(r0 + r) * C + c0 + c4);
        lds[r][c4] = v.x; lds[r][c4 + 1] = v.y; lds[r][c4 + 2] = v.z; lds[r][c4 + 3] = v.w;
    }
    __syncthreads();
    const int lane = tid & 63, wid = tid >> 6;
#pragma unroll
    for (int j = 0; j < 4; ++j) {
        int s = wid * 4 + j;
        int ig_l = s >> 3, ks_l = s & 7;
        int r = ig_l * 16 + (lane & 15);
        int c = ks_l * 32 + ((lane >> 4) << 3);
        unsigned short o[8];
#pragma unroll
        for (int e = 0; e < 8; ++e) o[e] = f2bf(lds[r][c + e]);
        size_t ig = rt * 2 + ig_l, ks = (size_t)ct * 8 + ks_l;
        *(short8*)(dst + ((ig * KS + ks) * 64 + lane) * 8) = *(short8*)o;
    }
}

// ============================================================================
// conv_qr_fp8
// ============================================================================
__global__ __launch_bounds__(256)
void conv_qr_fp8(const float* __restrict__ src, unsigned char* __restrict__ dst) {
    __shared__ float lds[32][258];
    const int tid = threadIdx.x;
    const int rt = blockIdx.x / 6, ct = blockIdx.x - rt * 6;
    const int r0 = rt * 32, c0 = ct * 256;
#pragma unroll
    for (int it = 0; it < 8; ++it) {
        int fid = it * 256 + tid;
        int r = fid >> 6, c4 = (fid & 63) << 2;
        float4 v = *(const float4*)(src + (size_t)(r0 + r) * QLR_K + c0 + c4);
        lds[r][c4] = v.x; lds[r][c4 + 1] = v.y; lds[r][c4 + 2] = v.z; lds[r][c4 + 3] = v.w;
    }
    __syncthreads();
    const int lane = tid & 63, wid = tid >> 6;
#pragma unroll
    for (int j = 0; j < 4; ++j) {
        int s = wid * 4 + j;
        int ig_l = s >> 3, ks_l = s & 7;
        int r = ig_l * 16 + (lane & 15);
        int c = ks_l * 32 + ((lane >> 4) << 3);
        uint2 o;
        o.x = pk4fp8(lds[r][c], lds[r][c + 1], lds[r][c + 2], lds[r][c + 3]);
        o.y = pk4fp8(lds[r][c + 4], lds[r][c + 5], lds[r][c + 6], lds[r][c + 7]);
        size_t ig = rt * 2 + ig_l, ks = (size_t)ct * 8 + ks_l;
        *(uint2*)(dst + ((ig * 48 + ks) * 64 + lane) * 8) = o;
    }
}

// ============================================================================
// conv_wq_fp8
// ============================================================================
__global__ __launch_bounds__(256)
void conv_wq_fp8(const float* __restrict__ wq, unsigned char* __restrict__ dst) {
    __shared__ float lds[32][258];
    const int tid = threadIdx.x;
    const int kt = blockIdx.x >> 5, nt = blockIdx.x & 31;
    const int k0 = kt * 32, n0 = nt * 256;
#pragma unroll
    for (int it = 0; it < 8; ++it) {
        int fid = it * 256 + tid;
        int k = fid >> 6, c4 = (fid & 63) << 2;
        float4 v = *(const float4*)(wq + (size_t)(k0 + k) * QN + n0 + c4);
        lds[k][c4] = v.x; lds[k][c4 + 1] = v.y; lds[k][c4 + 2] = v.z; lds[k][c4 + 3] = v.w;
    }
    __syncthreads();
    const int lane = tid & 63, wid = tid >> 6;
#pragma unroll
    for (int j = 0; j < 4; ++j) {
        int s = wid * 4 + j;
        int n_l = s * 16 + (lane & 15);
        int kb = (lane >> 4) << 3;
        uint2 o;
        o.x = pk4fp8(lds[kb][n_l], lds[kb + 1][n_l], lds[kb + 2][n_l], lds[kb + 3][n_l]);
        o.y = pk4fp8(lds[kb + 4][n_l], lds[kb + 5][n_l], lds[kb + 6][n_l], lds[kb + 7][n_l]);
        size_t ng = (size_t)nt * 16 + s;
        *(uint2*)(dst + ((ng * 48 + kt) * 64 + lane) * 8) = o;
    }
}

// ============================================================================
// conv_wkw
// ============================================================================
__global__ __launch_bounds__(256)
void conv_wkw(const float* __restrict__ wk, const float* __restrict__ wp,
              unsigned short* __restrict__ dst) {
    int gid = blockIdx.x * 4 + (threadIdx.x >> 6);
    int lane = threadIdx.x & 63;
    int ng = gid / 224, ks = gid - ng * 224;
    int col = ng * 16 + (lane & 15);
    int k = ks * 32 + ((lane >> 4) << 3);
    unsigned short o[8];
#pragma unroll
    for (int e = 0; e < 8; ++e) {
        float v = (col < 128) ? wk[(size_t)(k + e) * 128 + col]
                              : wp[(size_t)(k + e) * 64 + (col - 128)];
        o[e] = f2bf(v);
    }
    *(short8*)(dst + ((size_t)gid * 64 + lane) * 8) = *(short8*)o;
}

// ============================================================================
// kw_gemm_mfma
// ============================================================================
__global__ __launch_bounds__(256)
void kw_gemm_mfma(const unsigned short* __restrict__ hsfrag,
                  const unsigned short* __restrict__ wkwfrag,
                  float* __restrict__ part) {
    const int kz = blockIdx.x, mt = blockIdx.y;
    const int lane = threadIdx.x & 63, wid = threadIdx.x >> 6;
    const int ig = mt * 4 + wid;
    const f32x4 zed = {0.f, 0.f, 0.f, 0.f};
    f32x4 acc[12];
#pragma unroll
    for (int n = 0; n < 12; ++n) acc[n] = zed;
    for (int ks = kz * 56; ks < kz * 56 + 56; ++ks) {
        short8 a = *(const short8*)(hsfrag + (((size_t)ig * 224 + ks) * 64 + lane) * 8);
#pragma unroll
        for (int ng = 0; ng < 12; ++ng) {
            short8 b = *(const short8*)(wkwfrag + (((size_t)ng * 224 + ks) * 64 + lane) * 8);
            acc[ng] = MFMA16(a, b, acc[ng]);
        }
    }
    const int colc = lane & 15, rsub = (lane >> 4) << 2;
    float* pb = part + (size_t)kz * T_DIM * 192;
#pragma unroll
    for (int ng = 0; ng < 12; ++ng)
#pragma unroll
        for (int r = 0; r < 4; ++r) {
            int row = ig * 16 + rsub + r;
            pb[(size_t)row * 192 + ng * 16 + colc] = acc[ng][r];
        }
}

// ============================================================================
// reduce_w
// ============================================================================
__global__ __launch_bounds__(256)
void reduce_w(const float* __restrict__ part, float* __restrict__ wT) {
    __shared__ float lds[64][65];
    const int r0 = blockIdx.x * 64;
    const int tid = threadIdx.x;
#pragma unroll
    for (int it = 0; it < 16; ++it) {
        int fid = it * 256 + tid;
        int rl = fid >> 6, h = fid & 63;
        float s = 0.f;
#pragma unroll
        for (int z = 0; z < 4; ++z)
            s += part[((size_t)z * T_DIM + r0 + rl) * 192 + 128 + h];
        lds[rl][h] = s * WSCALE;
    }
    __syncthreads();
#pragma unroll
    for (int it = 0; it < 16; ++it) {
        int fid = it * 256 + tid;
        int h = fid >> 6, rl = fid & 63;
        wT[(size_t)h * T_DIM + r0 + rl] = lds[rl][h];
    }
}

// ============================================================================
// ln_rope_k
// ============================================================================
__global__ __launch_bounds__(256)
void ln_rope_k(const float* __restrict__ part, const float2* __restrict__ tab,
               const float* __restrict__ gamma, const float* __restrict__ beta,
               unsigned char* __restrict__ kfrag) {
    __shared__ float ln[4][128];
    const int tid = threadIdx.x;
    const int wr = tid >> 6, lane = tid & 63;
    const int row = blockIdx.x * 4 + wr;
    float2 v = make_float2(0.f, 0.f);
#pragma unroll
    for (int z = 0; z < 4; ++z) {
        float2 p = *(const float2*)(part + ((size_t)z * T_DIM + row) * 192 + lane * 2);
        v.x += p.x; v.y += p.y;
    }
    float s = v.x + v.y;
#pragma unroll
    for (int off = 1; off < 64; off <<= 1) s += __shfl_xor(s, off);
    float mu = s * (1.0f / 128.0f);
    float d0 = v.x - mu, d1 = v.y - mu;
    float s2 = d0 * d0 + d1 * d1;
#pragma unroll
    for (int off = 1; off < 64; off <<= 1) s2 += __shfl_xor(s2, off);
    float rstd = 1.0f / sqrtf(s2 * (1.0f / 128.0f) + 1e-6f);
    ln[wr][lane * 2]     = d0 * rstd * gamma[lane * 2]     + beta[lane * 2];
    ln[wr][lane * 2 + 1] = d1 * rstd * gamma[lane * 2 + 1] + beta[lane * 2 + 1];
    __syncthreads();
    int d = lane * 2;
    float o0, o1;
    float v0 = ln[wr][d], v1 = ln[wr][d + 1];
    if (d < 64) {
        int dd = d & 31;
        float2 c0 = tab[(size_t)row * 32 + dd];
        float2 c1 = tab[(size_t)row * 32 + dd + 1];
        if (d < 32) {
            o0 = v0 * c0.x - ln[wr][d + 32] * c0.y;
            o1 = v1 * c1.x - ln[wr][d + 33] * c1.y;
        } else {
            o0 = v0 * c0.x + ln[wr][d - 32] * c0.y;
            o1 = v1 * c1.x + ln[wr][d - 31] * c1.y;
        }
    } else { o0 = v0; o1 = v1; }
    int jg = row >> 4, ks = d >> 5, sub = d & 31;
    int lp = ((sub >> 3) << 4) + (row & 15);
    size_t bidx = (((size_t)jg * 4 + ks) * 64 + lp) * 8 + (sub & 7);
    unsigned pk = (unsigned)__builtin_amdgcn_cvt_pk_fp8_f32(o0, o1, 0, false);
    *(unsigned short*)(kfrag + bidx) = (unsigned short)(pk & 0xFFFFu);
}

// ============================================================================
// q_gemm_mfma: fp8 x fp8 -> qfrag fp8 A-frag
// ============================================================================
__global__ __launch_bounds__(256, 4)
void q_gemm_mfma(const unsigned char* __restrict__ qr8,
                 const unsigned char* __restrict__ wq8,
                 const float2* __restrict__ tab,
                 unsigned char* __restrict__ qfrag) {
    const int hw = blockIdx.x;
    const int orig = (hw & 7) * 256 + (hw >> 3);
    const int head = orig >> 5, mt = orig & 31;
    const int tid = threadIdx.x, lane = tid & 63, wid = tid >> 6;
    const int wm = wid >> 1, wn = wid & 1;
    const f32x4 zed = {0.f, 0.f, 0.f, 0.f};
    f32x4 acc[4][4];
#pragma unroll
    for (int m = 0; m < 4; m++)
#pragma unroll
        for (int n = 0; n < 4; n++) acc[m][n] = zed;

    const int ig0 = mt * 8 + wm * 4;
    const int ng0 = head * 8 + wn * 4;
    const unsigned char* ap = qr8 + ((size_t)ig0 * 48 * 64 + lane) * 8;
    const unsigned char* bp = wq8 + ((size_t)ng0 * 48 * 64 + lane) * 8;
    for (int ks = 0; ks < 48; ++ks) {
        long a[4], b[4];
#pragma unroll
        for (int m = 0; m < 4; m++)
            a[m] = *(const long*)(ap + ((size_t)m * 48 + ks) * 512);
#pragma unroll
        for (int n = 0; n < 4; n++)
            b[n] = *(const long*)(bp + ((size_t)n * 48 + ks) * 512);
#pragma unroll
        for (int m = 0; m < 4; m++)
#pragma unroll
            for (int n = 0; n < 4; n++)
                acc[m][n] = MFMA8(a[m], b[n], acc[m][n]);
    }
    const int colc = lane & 15;
    const int rsub = (lane >> 4) << 2;
#pragma unroll
    for (int m = 0; m < 4; m++) {
#pragma unroll
        for (int r = 0; r < 4; r++) {
            int row = mt * 128 + wm * 64 + m * 16 + rsub + r;
            int rl = rsub + r;
            size_t base = ((size_t)(row >> 4) * 64 + head) * 4;
            if (wn == 0) {
#pragma unroll
                for (int n2 = 0; n2 < 2; n2++) {
                    int dd = n2 * 16 + colc;
                    float2 cs = tab[(size_t)row * 32 + dd];
                    float x1 = acc[m][n2][r], x2 = acc[m][n2 + 2][r];
                    float olo = x1 * cs.x - x2 * cs.y;
                    float ohi = x2 * cs.x + x1 * cs.y;
                    int lp = ((dd >> 3) << 4) + rl;
                    qfrag[((base + 0) * 64 + lp) * 8 + (dd & 7)] = f2fp8(olo);
                    qfrag[((base + 1) * 64 + lp) * 8 + (dd & 7)] = f2fp8(ohi);
                }
            } else {
#pragma unroll
                for (int n = 0; n < 4; n++) {
                    int d = 64 + n * 16 + colc;
                    int ks2 = d >> 5, sub = d & 31;
                    int lp = ((sub >> 3) << 4) + rl;
                    qfrag[((base + ks2) * 64 + lp) * 8 + (sub & 7)] = f2fp8(acc[m][n][r]);
                }
            }
        }
    }
}

// ============================================================================
// scores_fill
// ============================================================================
__global__ __launch_bounds__(256)
void scores_fill(float* __restrict__ S) {
    const int bx = blockIdx.x, by = blockIdx.y;
    if (bx <= by) return;
    const int tid = threadIdx.x;
    float4 mv = make_float4(MASK_VAL, MASK_VAL, MASK_VAL, MASK_VAL);
#pragma unroll
    for (int l = 0; l < 16; l++) {
        int idx = l * 256 + tid;
        int r = idx >> 5, cg = idx & 31;
        *(float4*)(S + (size_t)(by * 128 + r) * T_DIM + bx * 128 + cg * 4) = mv;
    }
}

// ============================================================================
// scores_mfma v5: barrier-free, compact triangular grid (528 blocks).
// ============================================================================
__global__ __launch_bounds__(256, 3)
void scores_mfma(const unsigned char* __restrict__ qfrag,
                 const unsigned char* __restrict__ kfrag,
                 const float* __restrict__ wT, float* __restrict__ S) {
    int bid = blockIdx.x;                        // 0..527
    int by = (int)((sqrtf(8.f * bid + 1.f) - 1.f) * 0.5f);
    while ((by + 1) * (by + 2) / 2 <= bid) ++by;
    while (by * (by + 1) / 2 > bid) --by;
    const int jt = bid - by * (by + 1) / 2;
    __shared__ float wlds[64][128];
    const int tid = threadIdx.x;
    const int lane = tid & 63, wid = tid >> 6;
    const int wm = wid >> 1, wn = wid & 1;
    const int i0 = by * 128, j0 = jt * 128;
    const f32x4 zed = {0.f, 0.f, 0.f, 0.f};
#pragma unroll
    for (int it = 0; it < 32; ++it) {
        int fid = it * 256 + tid;
        int hh = fid >> 7, rl = fid & 127;
        wlds[hh][rl] = wT[(size_t)hh * T_DIM + i0 + rl];
    }
    long kf[4][4];
#pragma unroll
    for (int n = 0; n < 4; ++n) {
        int jg = (j0 >> 4) + wn * 4 + n;
#pragma unroll
        for (int ks = 0; ks < 4; ++ks)
            kf[n][ks] = *(const long*)(kfrag + (((size_t)jg * 4 + ks) * 64 + lane) * 8);
    }
    __syncthreads();

    f32x4 acc[4][4];
#pragma unroll
    for (int m = 0; m < 4; m++)
#pragma unroll
        for (int n = 0; n < 4; n++) acc[m][n] = zed;

    const int rsub = (lane >> 4) << 2;
    const unsigned char* qb[4];
#pragma unroll
    for (int m = 0; m < 4; ++m) {
        int ig = by * 8 + wm * 4 + m;
        qb[m] = qfrag + (size_t)ig * 64 * 2048 + lane * 8;
    }
    for (int h = 0; h < NH; ++h) {
#pragma unroll
        for (int m = 0; m < 4; ++m) {
            const unsigned char* qp = qb[m] + (size_t)h * 2048;
            long a[4];
#pragma unroll
            for (int ks = 0; ks < 4; ++ks)
                a[ks] = *(const long*)(qp + ks * 512);
            f32x4 s[4] = {zed, zed, zed, zed};
#pragma unroll
            for (int ks = 0; ks < 4; ++ks)
#pragma unroll
                for (int n = 0; n < 4; ++n)
                    s[n] = MFMA8(a[ks], kf[n][ks], s[n]);
            f32x4 wv = *(const f32x4*)&wlds[h][wm * 64 + m * 16 + rsub];
#pragma unroll
            for (int n = 0; n < 4; ++n)
#pragma unroll
                for (int rr = 0; rr < 4; ++rr)
                    acc[m][n][rr] += wv[rr] * fmaxf(s[n][rr], 0.0f);
        }
    }
    const int colc = lane & 15;
#pragma unroll
    for (int m = 0; m < 4; m++) {
#pragma unroll
        for (int n = 0; n < 4; n++) {
            int col = j0 + wn * 64 + n * 16 + colc;
#pragma unroll
            for (int rr = 0; rr < 4; rr++) {
                int row = i0 + wm * 64 + m * 16 + rsub + rr;
                float v = acc[m][n][rr];
                if (col > row) v = MASK_VAL;
                S[(size_t)row * T_DIM + col] = v;
            }
        }
    }
}

// ============================================================================
// topk v4: hybrid register/shuffle/LDS bitonic.
// Thread owns 4 consecutive keys. j<=2 in regs, j=4..128 via shfl_xor
// (partner = tid ^ (j/4)), j>=256 via LDS uint4 exchange. Same network as
// v2/v3 (verified), ~3x fewer instructions, ~0 bank conflicts.
// Blocks 0..1023: TWO rows < 2048 (512 threads each). Blocks 1024..3071:
// one row >= 2048 (full 4096 sort + top-half merge).
// ============================================================================
__device__ __forceinline__ void ce(unsigned &x, unsigned &y, bool up) {
    unsigned lo = x < y ? x : y, hi = x < y ? y : x;
    x = up ? lo : hi; y = up ? hi : lo;
}
__device__ __forceinline__ unsigned cd(unsigned a, unsigned b, bool keep_lo) {
    unsigned lo = a < b ? a : b, hi = a < b ? b : a;
    return keep_lo ? lo : hi;
}

__global__ __launch_bounds__(1024)
void topk_kernel(const float* __restrict__ S, float* __restrict__ outIdx) {
    __shared__ unsigned lds[4096];
    const int bid = blockIdx.x;
    const int tid = threadIdx.x;

    unsigned q0, q1, q2, q3;
    int row; unsigned e0; unsigned* L; bool act;

    if (bid < 1024) {            // two short rows per block
        const int half = tid >> 9;
        row = bid * 2 + half;
        e0 = 4u * (tid & 511);
        L = &lds[half * 2048];
        act = true;
    } else {                     // one long row
        row = bid + 1024;
        e0 = 4u * tid;
        L = lds;
        act = true;
    }
    const unsigned N = (bid < 1024) ? 2048u : 4096u;

    {   // load + pack keys + stages k=2,4
        float4 f = *(const float4*)(S + (size_t)row * T_DIM + e0);
        const float* fp = &f.x;
        unsigned qq[4];
#pragma unroll
        for (int e = 0; e < 4; ++e) {
            unsigned u = __float_as_uint(fp[e]);
            u = (u & 0x80000000u) ? ~u : (u | 0x80000000u);
            qq[e] = ((~u) & 0xFFFFF000u) | (e0 + e);
        }
        q0 = qq[0]; q1 = qq[1]; q2 = qq[2]; q3 = qq[3];
        ce(q0, q1, true); ce(q2, q3, false);           // k=2
        bool up4 = (e0 & 4u) == 0;                     // k=4
        ce(q0, q2, up4); ce(q1, q3, up4);
        ce(q0, q1, up4); ce(q2, q3, up4);
    }

    for (unsigned k = 8; k <= 2048u; k <<= 1) {
        for (unsigned j = k >> 1; j >= 4u; j >>= 1) {
            bool kl = ((e0 & k) == 0) ^ ((e0 & j) != 0);
            if (j >= 256u) {
                __syncthreads();
                *(uint4*)&L[e0] = make_uint4(q0, q1, q2, q3);
                __syncthreads();
                uint4 p = *(uint4*)&L[e0 ^ j];
                q0 = cd(q0, p.x, kl); q1 = cd(q1, p.y, kl);
                q2 = cd(q2, p.z, kl); q3 = cd(q3, p.w, kl);
            } else {
                int m = (int)(j >> 2);
                q0 = cd(q0, (unsigned)__shfl_xor((int)q0, m), kl);
                q1 = cd(q1, (unsigned)__shfl_xor((int)q1, m), kl);
                q2 = cd(q2, (unsigned)__shfl_xor((int)q2, m), kl);
                q3 = cd(q3, (unsigned)__shfl_xor((int)q3, m), kl);
            }
        }
        bool up = ((e0 & k) == 0);                     // j=2,1 in regs
        ce(q0, q2, up); ce(q1, q3, up);
        ce(q0, q1, up); ce(q2, q3, up);
    }

    if (N == 4096u) {
        // merge k=4096: mins into lower half, then sort lower 2048 ascending
        __syncthreads();
        *(uint4*)&lds[e0] = make_uint4(q0, q1, q2, q3);
        __syncthreads();
        const bool low = e0 < 2048u;
        if (low) {
            uint4 p = *(uint4*)&lds[e0 + 2048];
            q0 = q0 < p.x ? q0 : p.x; q1 = q1 < p.y ? q1 : p.y;
            q2 = q2 < p.z ? q2 : p.z; q3 = q3 < p.w ? q3 : p.w;
        }
        for (unsigned j = 1024; j >= 256u; j >>= 1) {
            __syncthreads();
            if (low) *(uint4*)&lds[e0] = make_uint4(q0, q1, q2, q3);
            __syncthreads();
            if (low) {
                uint4 p = *(uint4*)&lds[e0 ^ j];
                bool kl = (e0 & j) == 0;
                q0 = cd(q0, p.x, kl); q1 = cd(q1, p.y, kl);
                q2 = cd(q2, p.z, kl); q3 = cd(q3, p.w, kl);
            }
        }
        if (low) {
#pragma unroll
            for (unsigned j = 128; j >= 4u; j >>= 1) {
                bool kl = (e0 & j) == 0;
                int m = (int)(j >> 2);
                q0 = cd(q0, (unsigned)__shfl_xor((int)q0, m), kl);
                q1 = cd(q1, (unsigned)__shfl_xor((int)q1, m), kl);
                q2 = cd(q2, (unsigned)__shfl_xor((int)q2, m), kl);
                q3 = cd(q3, (unsigned)__shfl_xor((int)q3, m), kl);
            }
            ce(q0, q2, true); ce(q1, q3, true);
            ce(q0, q1, true); ce(q2, q3, true);
            float4 o = make_float4((float)(q0 & 0xFFFu), (float)(q1 & 0xFFFu),
                                   (float)(q2 & 0xFFFu), (float)(q3 & 0xFFFu));
            *(float4*)(outIdx + (size_t)row * TOPK_N + e0) = o;
        }
    } else {
        float4 o = make_float4((float)(q0 & 0xFFFu), (float)(q1 & 0xFFFu),
                               (float)(q2 & 0xFFFu), (float)(q3 & 0xFFFu));
        *(float4*)(outIdx + (size_t)row * TOPK_N + e0) = o;
    }
}

// ============================================================================
extern "C" void kernel_launch(void* const* d_in, const int* in_sizes, int n_in,
                              void* d_out, int out_size, void* d_ws, size_t ws_size,
                              hipStream_t stream) {
    const float* hs      = (const float*)d_in[0];
    const float* qr      = (const float*)d_in[1];
    const int*   pos     = (const int*)  d_in[2];
    const float* wq_b    = (const float*)d_in[3];
    const float* wk      = (const float*)d_in[4];
    const float* k_gamma = (const float*)d_in[5];
    const float* k_beta  = (const float*)d_in[6];
    const float* w_proj  = (const float*)d_in[7];

    float* out     = (float*)d_out;
    float* out_idx = out;
    float* S       = out + (size_t)T_DIM * TOPK_N;

    char* wsp = (char*)d_ws;
    unsigned char*  qfrag  = (unsigned char*)wsp;  wsp += (size_t)67108864;
    unsigned short* hsfrag = (unsigned short*)qfrag;  // alias: hs consumed before qfrag written
    unsigned char*  qrfrag = (unsigned char*)wsp;  wsp += (size_t)12582912;
    unsigned char*  wqfrag = (unsigned char*)wsp;  wsp += (size_t)25165824;
    unsigned short* wkwfrag= (unsigned short*)wsp; wsp += (size_t)2752512;
    float*          part   = (float*)wsp;          wsp += (size_t)12582912;
    float*          wT     = (float*)wsp;          wsp += (size_t)1048576;
    unsigned char*  kfrag  = (unsigned char*)wsp;  wsp += (size_t)1048576;
    float2*         tab    = (float2*)wsp;         wsp += (size_t)1048576;

    rope_tab_kernel<<<512, 256, 0, stream>>>(pos, tab);
    conv_afrag <<<3584, 256, 0, stream>>>(hs, hsfrag, HSZ, 224, 28);
    conv_wkw   <<<672,  256, 0, stream>>>(wk, w_proj, wkwfrag);
    kw_gemm_mfma<<<dim3(4, 64), 256, 0, stream>>>(hsfrag, wkwfrag, part);
    reduce_w   <<<64,   256, 0, stream>>>(part, wT);
    ln_rope_k  <<<T_DIM / 4, 256, 0, stream>>>(part, tab, k_gamma, k_beta, kfrag);
    conv_qr_fp8<<<768,  256, 0, stream>>>(qr, qrfrag);
    conv_wq_fp8<<<1536, 256, 0, stream>>>(wq_b, wqfrag);
    q_gemm_mfma<<<2048, 256, 0, stream>>>(qrfrag, wqfrag, tab, qfrag);
    scores_fill<<<dim3(32, 32), 256, 0, stream>>>(S);
    scores_mfma<<<528, 256, 0, stream>>>(qfrag, kfrag, wT, S);
    topk_kernel<<<3072, 1024, 0, stream>>>(S, out_idx);
}